// Round 6
// baseline (308.895 us; speedup 1.0000x reference)
//
#include <hip/hip_runtime.h>
#include <math.h>

// ---------- types ----------
typedef __bf16 bf16_t;
typedef bf16_t bf16x8 __attribute__((ext_vector_type(8)));
typedef float  f32x4  __attribute__((ext_vector_type(4)));
typedef unsigned short u16;
typedef u16 ushortx4 __attribute__((ext_vector_type(4)));
typedef unsigned long long u64;

#define MFMA16(a, b, c) __builtin_amdgcn_mfma_f32_16x16x32_bf16((a), (b), (c), 0, 0, 0)

__device__ __forceinline__ u16 f2bf(float f) {
    unsigned int u = __float_as_uint(f);
    u = (u + 0x7fffu + ((u >> 16) & 1u)) >> 16;
    return (u16)u;
}

__device__ __forceinline__ float bf2f(unsigned int u) {
    return __uint_as_float(u << 16);
}

// async global->LDS, 16B per lane; lds dest = wave-uniform base + lane*16
__device__ __forceinline__ void gld16(const u16* g, u16* l) {
    __builtin_amdgcn_global_load_lds(
        (const __attribute__((address_space(1))) void*)g,
        (__attribute__((address_space(3))) void*)l, 16, 0, 0);
}

// B=2, L=2048, D_MODEL=1024, H=16, DH=64, HB=32
// ws map (MB):  [phase-aware reuse]
//  qb 0-8, kb 8-16, vb 16-24        (dead after k_proj)
//  wqt 24-26 wkt 26-28 wvt 28-30    (dead after k_proj)
//  wot 30-32                        (alive until k_out)
//  qh 32-40 (scaled by log2e/8), kh 40-48, vt 48-56 (dead after k_attn)
//  ao 56-64                          (alive until k_out)
//  mfrag 64-65                       (dead after k_attn)
//  po 0-16 (over qb/kb), pl 16-17 (over vb)   [k_attn out, dead after k_amerge]
//  xp0 32-48 (over qh/kh), xp1 64-80 (over mfrag)  [k_out partials -> k_ln]
//
// K-row permutation pi (within each 64-row K tile), applied at k_attn staging:
//   M-position m = [t1 t0 q1 q0 r1 r0] holds K-row pi(m) = [t1 q1 q0 t0 r1 r0].
// Score-MFMA slot (t, quad, r) then carries k = (t>>1)*32 + quad*8 + (t&1)*4 + r,
// so each lane's 16 P values are exactly its two 8-wide PV A-fragment slices:
// P routing is pure intra-lane register packing (verified round 3).
//
// mfrag: fragment-ordered mask words (verified round 5). Word
// W = ((b*64+qbi)*32 + ktile)*32 + hfo*16 + (t*4+r); bit L=(quad*16+l15) of W =
//   mask[b][qbi*32 + hfo*16 + l15][ktile*64 + quad*8 + (t>>1)*32 + (t&1)*4 + r]
// One qbi (32 q-rows) spans 1024 words. k_attn applies each word with ONE
// v_cndmask_b32 from an SGPR pair (s_load via wave-uniform AS(4) pointer).
//
// Round 6: 64 Q rows per wave (hf 0..3), qt grid 16->8 (512 blocks). Doubles
// MFMA+VALU work per K/V LDS read and per barrier interval; halves barrier
// events and K/V refetch per CU. Pure index-math extension of r5.

// ---------- fused: fp32->bf16 cvt for q,k,v + pi-ordered mask ballots + weight transposes ----------
__global__ __launch_bounds__(256) void k_prep(const float* __restrict__ q,
                                              const float* __restrict__ k,
                                              const float* __restrict__ v,
                                              const int* __restrict__ mask,
                                              const float* __restrict__ w_q,
                                              const float* __restrict__ w_k,
                                              const float* __restrict__ w_v,
                                              const float* __restrict__ w_o,
                                              u16* __restrict__ qb,
                                              u16* __restrict__ kb,
                                              u16* __restrict__ vb,
                                              u64* __restrict__ mfrag,
                                              u16* __restrict__ wqt,
                                              u16* __restrict__ wkt,
                                              u16* __restrict__ wvt,
                                              u16* __restrict__ wot) {
    __shared__ float tile[32][33];
    int bid = blockIdx.x;
    if (bid < 12288) {
        int sel = bid >> 12;                 // 0..2
        int i = (bid & 4095) * 256 + threadIdx.x;
        const float* src = sel == 0 ? q : (sel == 1 ? k : v);
        u16* dst = sel == 0 ? qb : (sel == 1 ? kb : vb);
        float4 val = ((const float4*)src)[i];
        ushortx4 r;
        r[0] = f2bf(val.x); r[1] = f2bf(val.y); r[2] = f2bf(val.z); r[3] = f2bf(val.w);
        ((ushortx4*)dst)[i] = r;
    } else if (bid < 14336) {
        // pi-ordered fragment mask ballots (see header comment)
        int wave = threadIdx.x >> 6, lane = threadIdx.x & 63;
        int l15 = lane & 15, quad = lane >> 4;
        int wt = (bid - 12288) * 4 + wave;   // [0, 8192)
        int hf = wt & 1;
        int g = wt >> 1;                     // (b*64+qbi)*32 + ktile
        int ktile = g & 31, qbi = (g >> 5) & 63, b = g >> 11;
        int qq = qbi * 32 + hf * 16 + l15;
        const int* mrow = mask + ((size_t)(b * 2048 + qq)) * 2048 + ktile * 64 + quad * 8;
        u64 myw = 0;
#pragma unroll
        for (int t = 0; t < 4; ++t)
#pragma unroll
            for (int r = 0; r < 4; ++r) {
                int m = mrow[(t >> 1) * 32 + (t & 1) * 4 + r];
                u64 bal = __ballot(m != 0);
                if (lane == t * 4 + r) myw = bal;
            }
        if (lane < 16) mfrag[(size_t)g * 32 + hf * 16 + lane] = myw;
    } else {
        int b3 = bid - 14336;
        const float* src;
        u16* dst;
        int r0, c0, C;
        if (b3 < 3072) {
            int x = b3 & 31, y = (b3 >> 5) & 1, z = b3 >> 6;
            int h = z & 15, sel = z >> 4;
            src = (sel == 0 ? w_q : (sel == 1 ? w_k : w_v)) + (size_t)h * 65536;
            dst = (sel == 0 ? wqt : (sel == 1 ? wkt : wvt)) + (size_t)h * 65536;
            r0 = x * 32; c0 = y * 32; C = 64;
        } else {
            int t = b3 - 3072;
            r0 = (t & 31) * 32; c0 = (t >> 5) * 32; C = 1024;
            src = w_o; dst = wot;
        }
        int tx = threadIdx.x & 31, ty = threadIdx.x >> 5;
        const float* s = src + ((size_t)r0) * C + c0;
#pragma unroll
        for (int i = 0; i < 4; ++i) tile[ty + i * 8][tx] = s[(ty + i * 8) * (size_t)C + tx];
        __syncthreads();
        u16* d = dst + ((size_t)c0) * 1024 + r0;
#pragma unroll
        for (int i = 0; i < 4; ++i) d[(ty + i * 8) * 1024 + tx] = f2bf(tile[tx][ty + i * 8]);
    }
}

// ---------- GEMM core body (uses As, Bs u16* into shared) ----------
#define GEMM_CORE(Ablk, Bblk, ACC)                                                    \
    int c0 = wave * 2;                                                                \
    const u16* Ag0 = Ablk + (size_t)(c0 * 16 + l15) * 1024 + quad * 8;                \
    const u16* Ag1 = Ablk + (size_t)((c0 + 1) * 16 + l15) * 1024 + quad * 8;          \
    const u16* Bg0 = Bblk + (size_t)(c0 * 16 + l15) * 1024 + quad * 8;                \
    const u16* Bg1 = Bblk + (size_t)((c0 + 1) * 16 + l15) * 1024 + quad * 8;          \
    gld16(Ag0, As + c0 * 512); gld16(Ag1, As + (c0 + 1) * 512);                       \
    gld16(Bg0, Bs + c0 * 512); gld16(Bg1, Bs + (c0 + 1) * 512);                       \
    __syncthreads();                                                                  \
    int buf = 0;                                                                      \
    for (int ks = 0; ks < 32; ++ks) {                                                 \
        if (ks < 31) {                                                                \
            int k0 = (ks + 1) * 32;                                                   \
            gld16(Ag0 + k0, As + (buf ^ 1) * 4096 + c0 * 512);                        \
            gld16(Ag1 + k0, As + (buf ^ 1) * 4096 + (c0 + 1) * 512);                  \
            gld16(Bg0 + k0, Bs + (buf ^ 1) * 4096 + c0 * 512);                        \
            gld16(Bg1 + k0, Bs + (buf ^ 1) * 4096 + (c0 + 1) * 512);                  \
        }                                                                             \
        bf16x8 af[4], bfr[4];                                                         \
        _Pragma("unroll")                                                             \
        for (int i = 0; i < 4; ++i)                                                   \
            af[i] = *(const bf16x8*)(As + buf * 4096 + (wy * 4 + i) * 512 + lane * 8);\
        _Pragma("unroll")                                                             \
        for (int j = 0; j < 4; ++j)                                                   \
            bfr[j] = *(const bf16x8*)(Bs + buf * 4096 + (wx * 4 + j) * 512 + lane * 8);\
        _Pragma("unroll")                                                             \
        for (int i = 0; i < 4; ++i)                                                   \
            _Pragma("unroll")                                                         \
            for (int j = 0; j < 4; ++j) ACC[i][j] = MFMA16(af[i], bfr[j], ACC[i][j]); \
        __syncthreads();                                                              \
        buf ^= 1;                                                                     \
    }

// ---------- fused q/k/v projections, XCD-local A-tile reuse ----------
__global__ __launch_bounds__(256) void k_proj(
    const u16* __restrict__ qb, const u16* __restrict__ kb, const u16* __restrict__ vb,
    const u16* __restrict__ wqt, const u16* __restrict__ wkt, const u16* __restrict__ wvt,
    u16* __restrict__ oq, u16* __restrict__ okh, u16* __restrict__ ovt) {
    __shared__ __align__(16) u16 smem[18432];
    u16* As = smem;
    u16* Bs = smem + 8192;
    int z = blockIdx.y, gx = blockIdx.x;
    int bm, bn;
    const u16 *A, *B;
    // fastest-varying index = tile of the LARGE matrix -> its readers co-locate per XCD
    if (z == 0)      { bm = gx & 31; bn = gx >> 5; A = qb; B = wqt; }
    else if (z == 1) { bm = gx & 31; bn = gx >> 5; A = kb; B = wkt; }
    else             { bn = gx & 31; bm = gx >> 5; A = wvt; B = vb; }
    A += (size_t)bm * 128 * 1024;
    B += (size_t)bn * 128 * 1024;
    int tid = threadIdx.x, wave = tid >> 6, lane = tid & 63;
    int wy = wave >> 1, wx = wave & 1, l15 = lane & 15, quad = lane >> 4;
    f32x4 acc[4][4] = {};
    GEMM_CORE(A, B, acc)
    u16* ep = smem + wave * 4608;
    float mulf = (z == 0) ? 0.18033688011112042f : 1.0f;
#pragma unroll
    for (int i = 0; i < 4; ++i)
#pragma unroll
        for (int j = 0; j < 4; ++j)
#pragma unroll
            for (int r = 0; r < 4; ++r)
                ep[(i * 16 + quad * 4 + r) * 72 + j * 16 + l15] = f2bf(acc[i][j][r] * mulf);
    int rl = lane >> 3, cg = lane & 7;
    if (z < 2) {
        int hh = bn * 2 + wx;
        int m0 = bm * 128 + wy * 64;
        int bb = m0 >> 11, l0 = m0 & 2047;
        u16* O = (z ? okh : oq) + ((size_t)((hh * 2 + bb) * 2048 + l0)) * 64;
#pragma unroll
        for (int s = 0; s < 8; ++s) {
            int row = s * 8 + rl;
            uint4 v = *(const uint4*)(ep + row * 72 + cg * 8);
            *(uint4*)(O + (size_t)row * 64 + cg * 8) = v;
        }
    } else {
        int m0 = bm * 128 + wy * 64;
        int hh = m0 >> 6;
        int n0 = bn * 128 + wx * 64;
        int bb = n0 >> 11, l0 = n0 & 2047;
        u16* O = ovt + (size_t)(hh * 2 + bb) * 131072 + (size_t)(m0 & 63) * 2048 + l0;
#pragma unroll
        for (int s = 0; s < 8; ++s) {
            int row = s * 8 + rl;
            uint4 v = *(const uint4*)(ep + row * 72 + cg * 8);
            *(uint4*)(O + (size_t)row * 2048 + cg * 8) = v;
        }
    }
}

// ---------- flash attention: split-K=2, hb-fastest grid (XCD-local K/V) ----------
// grid (32 hb, 8 qt, 2 ks); 256 thr = 4 waves x 64 Q-rows (hf 0..3)
// pi-permuted K staging (r3) -> P in registers; mfrag SGPR-cndmask mask (r5).
__global__ __launch_bounds__(256) void k_attn(
    const u16* __restrict__ qh, const u16* __restrict__ kh,
    const u16* __restrict__ vt, const u64* __restrict__ mfrag,
    u16* __restrict__ po, float* __restrict__ pl) {
    int hb = blockIdx.x, qt = blockIdx.y, ksp = blockIdx.z;
    int b = hb & 1;
    int tid = threadIdx.x, wave = tid >> 6, lane = tid & 63;
    int l15 = lane & 15, quad = lane >> 4;

    __shared__ __align__(16) u16 Ks[2][4096], Vs[2][4096];
    __shared__ __align__(16) u16 Eb[4][1024];   // epilogue scratch (swizzled)

    int qrow0 = qt * 256 + wave * 64;
    const u16* Qp = qh + ((size_t)(hb * 2048) + qrow0 + l15) * 64 + quad * 8;
    bf16x8 qf[4][2];
#pragma unroll
    for (int hf = 0; hf < 4; ++hf) {
        qf[hf][0] = *(const bf16x8*)(Qp + hf * 1024);
        qf[hf][1] = *(const bf16x8*)(Qp + hf * 1024 + 32);
    }

    int c0 = wave * 2;
    // pi-permuted K-row for this staging lane: [w1 l3 l2 w0 l1 l0]
    int rowp = (wave >> 1) * 32 + (l15 >> 2) * 8 + (wave & 1) * 4 + (l15 & 3);
    const u16* Kg0 = kh + (size_t)hb * 131072 + (size_t)ksp * 65536 +
                     (size_t)rowp * 64 + quad * 8;
    const u16* Kg1 = Kg0 + 32;
    const u16* Vg0 = vt + (size_t)hb * 131072 + (size_t)(wave * 16 + l15) * 2048 +
                     ksp * 1024 + quad * 8;
    const u16* Vg1 = Vg0 + 32;

    // wave-uniform mask-word pointer in constant addrspace -> s_load (SALU pipe)
    // base qbi0 = qt*8 + wave*2; word offset (hf>>1)*1024 + kt*32 + (hf&1)*16 + i
    int wu = __builtin_amdgcn_readfirstlane(wave);
    const __attribute__((address_space(4))) u64* Mw =
        (const __attribute__((address_space(4))) u64*)(mfrag +
            (size_t)((b * 64 + qt * 8 + wu * 2) * 1024 + ksp * 512));

    float l_lane[4] = {0.f, 0.f, 0.f, 0.f};
    f32x4 o[4][4] = {};
    float neg = -3e30f;

    gld16(Kg0, &Ks[0][c0 * 512]);
    gld16(Kg1, &Ks[0][(c0 + 1) * 512]);
    gld16(Vg0, &Vs[0][c0 * 512]);
    gld16(Vg1, &Vs[0][(c0 + 1) * 512]);
    __syncthreads();
    int buf = 0;
    for (int kt = 0; kt < 16; ++kt) {
        if (kt < 15) {
            gld16(Kg0 + (size_t)(kt + 1) * 4096, &Ks[buf ^ 1][c0 * 512]);
            gld16(Kg1 + (size_t)(kt + 1) * 4096, &Ks[buf ^ 1][(c0 + 1) * 512]);
            gld16(Vg0 + (size_t)(kt + 1) * 64, &Vs[buf ^ 1][c0 * 512]);
            gld16(Vg1 + (size_t)(kt + 1) * 64, &Vs[buf ^ 1][(c0 + 1) * 512]);
        }
        bf16x8 kf[8], vf[8];
#pragma unroll
        for (int c = 0; c < 8; ++c) kf[c] = *(const bf16x8*)&Ks[buf][c * 512 + lane * 8];
#pragma unroll
        for (int c = 0; c < 8; ++c) vf[c] = *(const bf16x8*)&Vs[buf][c * 512 + lane * 8];
#pragma unroll
        for (int hf = 0; hf < 4; ++hf) {
            u64 mw[16];
#pragma unroll
            for (int i = 0; i < 16; ++i)
                mw[i] = Mw[(hf >> 1) * 1024 + kt * 32 + (hf & 1) * 16 + i];
            f32x4 st[4] = {};
#pragma unroll
            for (int t = 0; t < 4; ++t) {
                st[t] = MFMA16(kf[t * 2], qf[hf][0], st[t]);
                st[t] = MFMA16(kf[t * 2 + 1], qf[hf][1], st[t]);
            }
            // one cndmask per element: bit[lane] of mfrag word (t*4+r) selects -3e30
            float p[16];
#pragma unroll
            for (int t = 0; t < 4; ++t)
#pragma unroll
                for (int r = 0; r < 4; ++r) {
                    float sc;
                    asm("v_cndmask_b32 %0, %1, %2, %3"
                        : "=v"(sc)
                        : "v"(st[t][r]), "v"(neg), "s"(mw[t * 4 + r]));
                    p[t * 4 + r] = __builtin_amdgcn_exp2f(sc);
                }
            // exp2 + verified manual bf16 pack, direct into PV A-fragments
            float ll = 0.f;
            unsigned int pw[8];
#pragma unroll
            for (int t = 0; t < 4; ++t) {
                float p0 = p[t * 4 + 0], p1 = p[t * 4 + 1];
                float p2 = p[t * 4 + 2], p3 = p[t * 4 + 3];
                ll += (p0 + p1) + (p2 + p3);
                pw[t * 2]     = (__float_as_uint(p1) & 0xffff0000u) | (__float_as_uint(p0) >> 16);
                pw[t * 2 + 1] = (__float_as_uint(p3) & 0xffff0000u) | (__float_as_uint(p2) >> 16);
            }
            l_lane[hf] += ll;
            union { unsigned int w[4]; bf16x8 v; } p0u, p1u;
            p0u.w[0] = pw[0]; p0u.w[1] = pw[1]; p0u.w[2] = pw[2]; p0u.w[3] = pw[3];
            p1u.w[0] = pw[4]; p1u.w[1] = pw[5]; p1u.w[2] = pw[6]; p1u.w[3] = pw[7];
#pragma unroll
            for (int t = 0; t < 4; ++t) {
                o[hf][t] = MFMA16(p0u.v, vf[t * 2], o[hf][t]);
                o[hf][t] = MFMA16(p1u.v, vf[t * 2 + 1], o[hf][t]);
            }
        }
        __syncthreads();
        buf ^= 1;
    }
    // ---- store partial l + unnormalized partial O (coalesced via swizzled Eb) ----
    size_t rowbase = ((size_t)ksp * 32 + hb) * 2048 + qrow0;
    int rl = lane >> 3, cg = lane & 7;
#pragma unroll
    for (int hf = 0; hf < 4; ++hf) {
        float ls = l_lane[hf];
        ls += __shfl_xor(ls, 16, 64);
        ls += __shfl_xor(ls, 32, 64);
        if (quad == 0) pl[rowbase + hf * 16 + l15] = ls;
#pragma unroll
        for (int t = 0; t < 4; ++t)
#pragma unroll
            for (int r = 0; r < 4; ++r) {
                int row = quad * 4 + r, col = t * 16 + l15;
                int g = col >> 3;
                Eb[wave][row * 64 + ((g ^ (row & 7)) << 3) + (col & 7)] =
                    f2bf(o[hf][t][r]);
            }
#pragma unroll
        for (int s = 0; s < 2; ++s) {
            int row = s * 8 + rl;
            uint4 v = *(const uint4*)&Eb[wave][row * 64 + ((cg ^ (row & 7)) << 3)];
            *(uint4*)(po + (rowbase + hf * 16 + row) * 64 + cg * 8) = v;
        }
    }
}

// ---------- split-K merge: ao = (po0+po1)/(l0+l1) ----------
__global__ __launch_bounds__(256) void k_amerge(const u16* __restrict__ po,
                                                const float* __restrict__ pl,
                                                u16* __restrict__ ao) {
    int bid = blockIdx.x;               // 32 hb x 64 row-chunks
    int hb = bid >> 6, rc = bid & 63;
    int h = hb >> 1, b = hb & 1;
    int tid = threadIdx.x;
    int r = tid >> 3, c = tid & 7;
    int row = rc * 32 + r;
    size_t i0 = ((size_t)hb * 2048 + row) * 64 + c * 8;
    uint4 a0 = *(const uint4*)(po + i0);
    uint4 a1 = *(const uint4*)(po + i0 + 4194304);
    float l0 = pl[(size_t)hb * 2048 + row];
    float l1 = pl[65536 + (size_t)hb * 2048 + row];
    float inv = 1.0f / (l0 + l1);
    unsigned int* pa0 = (unsigned int*)&a0;
    unsigned int* pa1 = (unsigned int*)&a1;
    uint4 out;
    unsigned int* po_ = (unsigned int*)&out;
#pragma unroll
    for (int i = 0; i < 4; ++i) {
        float lo = (bf2f(pa0[i] & 0xffffu) + bf2f(pa1[i] & 0xffffu)) * inv;
        float hi = (bf2f(pa0[i] >> 16) + bf2f(pa1[i] >> 16)) * inv;
        po_[i] = (unsigned int)f2bf(lo) | ((unsigned int)f2bf(hi) << 16);
    }
    *(uint4*)(ao + ((size_t)(b * 2048 + row)) * 1024 + h * 64 + c * 8) = out;
}

// ---------- output projection, split-K=2, raw fp32 partials, bm-fastest ----------
__global__ __launch_bounds__(512) void k_out(
    const u16* __restrict__ ao, const u16* __restrict__ wot,
    float* __restrict__ xp0, float* __restrict__ xp1) {
    __shared__ __align__(16) u16 smem[18432];
    u16* As = smem;
    u16* Bs = smem + 8192;
    int gx = blockIdx.x, bm = gx & 31, bn = gx >> 5;
    int ksp = blockIdx.y;
    const u16* A = ao + (size_t)bm * 128 * 1024 + ksp * 512;
    const u16* B = wot + (size_t)bn * 128 * 1024 + ksp * 512;
    float* xp = ksp ? xp1 : xp0;
    int tid = threadIdx.x, wave = tid >> 6, lane = tid & 63;
    int wy = wave >> 2, wx = wave & 3, l15 = lane & 15, quad = lane >> 4;
    const u16* Ag = A + (size_t)(wave * 16 + l15) * 1024 + quad * 8;
    const u16* Bg = B + (size_t)(wave * 16 + l15) * 1024 + quad * 8;
    f32x4 acc[4][2] = {};
    gld16(Ag, As + wave * 512);
    gld16(Bg, Bs + wave * 512);
    __syncthreads();
    int buf = 0;
    for (int ks = 0; ks < 16; ++ks) {
        if (ks < 15) {
            int k0 = (ks + 1) * 32;
            gld16(Ag + k0, As + (buf ^ 1) * 4096 + wave * 512);
            gld16(Bg + k0, Bs + (buf ^ 1) * 4096 + wave * 512);
        }
        bf16x8 af[4], bfr[2];
#pragma unroll
        for (int i = 0; i < 4; ++i)
            af[i] = *(const bf16x8*)(As + buf * 4096 + (wy * 4 + i) * 512 + lane * 8);
#pragma unroll
        for (int j = 0; j < 2; ++j)
            bfr[j] = *(const bf16x8*)(Bs + buf * 4096 + (wx * 2 + j) * 512 + lane * 8);
#pragma unroll
        for (int i = 0; i < 4; ++i)
#pragma unroll
            for (int j = 0; j < 2; ++j) acc[i][j] = MFMA16(af[i], bfr[j], acc[i][j]);
        __syncthreads();
        buf ^= 1;
    }
    float* epf = (float*)smem + wave * 1152;
    int rl = lane >> 3, cg = lane & 7;
    int mbase = bm * 128 + wy * 64, nbase = bn * 128 + wx * 32;
#pragma unroll
    for (int cc = 0; cc < 2; ++cc) {
#pragma unroll
        for (int i2 = 0; i2 < 2; ++i2)
#pragma unroll
            for (int j = 0; j < 2; ++j)
#pragma unroll
                for (int r = 0; r < 4; ++r)
                    epf[(i2 * 16 + quad * 4 + r) * 36 + j * 16 + l15] =
                        acc[cc * 2 + i2][j][r];
#pragma unroll
        for (int s = 0; s < 4; ++s) {
            int row = s * 8 + rl;
            f32x4 v = *(const f32x4*)(epf + row * 36 + cg * 4);
            int m = mbase + cc * 32 + row, n = nbase + cg * 4;
            *(f32x4*)(xp + (size_t)m * 1024 + n) = v;
        }
    }
}

// ---------- layernorm + split-K sum + bias + residual ----------
__global__ __launch_bounds__(256) void k_ln(const float* __restrict__ xp0,
                                            const float* __restrict__ xp1,
                                            const float* __restrict__ resid,
                                            const float* __restrict__ bo,
                                            const float* __restrict__ gamma,
                                            const float* __restrict__ beta,
                                            float* __restrict__ out) {
    int row = blockIdx.x;
    size_t base = (size_t)row * 256;
    float4 a0 = ((const float4*)xp0)[base + threadIdx.x];
    float4 a1 = ((const float4*)xp1)[base + threadIdx.x];
    float4 rs = ((const float4*)resid)[base + threadIdx.x];
    float4 b4 = ((const float4*)bo)[threadIdx.x];
    float4 v;
    v.x = a0.x + a1.x + rs.x + b4.x;
    v.y = a0.y + a1.y + rs.y + b4.y;
    v.z = a0.z + a1.z + rs.z + b4.z;
    v.w = a0.w + a1.w + rs.w + b4.w;
    float s = v.x + v.y + v.z + v.w;
    float ss = v.x * v.x + v.y * v.y + v.z * v.z + v.w * v.w;
#pragma unroll
    for (int off = 32; off; off >>= 1) {
        s += __shfl_down(s, off, 64);
        ss += __shfl_down(ss, off, 64);
    }
    __shared__ float sb[8];
    int wave = threadIdx.x >> 6, lane = threadIdx.x & 63;
    if (lane == 0) { sb[wave] = s; sb[4 + wave] = ss; }
    __syncthreads();
    s = sb[0] + sb[1] + sb[2] + sb[3];
    ss = sb[4] + sb[5] + sb[6] + sb[7];
    float mean = s * (1.0f / 1024.0f);
    float var = fmaxf((ss - 1024.0f * mean * mean) * (1.0f / 1023.0f), 0.f);
    float inv = 1.0f / (sqrtf(var) + 1e-3f);
    float4 g = ((const float4*)gamma)[threadIdx.x];
    float4 bt = ((const float4*)beta)[threadIdx.x];
    float4 o;
    o.x = (v.x - mean) * inv * g.x + bt.x;
    o.y = (v.y - mean) * inv * g.y + bt.y;
    o.z = (v.z - mean) * inv * g.z + bt.z;
    o.w = (v.w - mean) * inv * g.w + bt.w;
    ((float4*)(out))[base + threadIdx.x] = o;
}

// ---------- launch ----------
extern "C" void kernel_launch(void* const* d_in, const int* in_sizes, int n_in,
                              void* d_out, int out_size, void* d_ws, size_t ws_size,
                              hipStream_t stream) {
    const float* v_in  = (const float*)d_in[0];
    const float* k_in  = (const float*)d_in[1];
    const float* q_in  = (const float*)d_in[2];
    const int*   mask  = (const int*)d_in[3];
    const float* w_q   = (const float*)d_in[4];
    const float* w_k   = (const float*)d_in[5];
    const float* w_v   = (const float*)d_in[6];
    const float* w_o   = (const float*)d_in[7];
    const float* b_o   = (const float*)d_in[8];
    const float* gamma = (const float*)d_in[9];
    const float* beta  = (const float*)d_in[10];
    float* out = (float*)d_out;

    char* ws = (char*)d_ws;
    const size_t MB = 1ull << 20;
    u16* qb  = (u16*)(ws + 0 * MB);
    u16* kb  = (u16*)(ws + 8 * MB);
    u16* vb  = (u16*)(ws + 16 * MB);
    u16* wqt = (u16*)(ws + 24 * MB);
    u16* wkt = (u16*)(ws + 26 * MB);
    u16* wvt = (u16*)(ws + 28 * MB);
    u16* wot = (u16*)(ws + 30 * MB);
    u16* qh  = (u16*)(ws + 32 * MB);
    u16* kh  = (u16*)(ws + 40 * MB);
    u16* vt  = (u16*)(ws + 48 * MB);
    u16* ao  = (u16*)(ws + 56 * MB);
    u64* mfrag = (u64*)(ws + 64 * MB);
    u16*   po = (u16*)(ws + 0 * MB);     // over qb/kb (dead after k_proj)
    float* pl = (float*)(ws + 16 * MB);  // over vb (dead after k_proj)
    float* xp0 = (float*)(ws + 32 * MB); // over qh/kh (dead after k_attn)
    float* xp1 = (float*)(ws + 64 * MB); // over mfrag (dead after k_attn)

    k_prep<<<dim3(18432), dim3(256), 0, stream>>>(q_in, k_in, v_in, mask,
                                                  w_q, w_k, w_v, w_o,
                                                  qb, kb, vb, mfrag,
                                                  wqt, wkt, wvt, wot);
    k_proj<<<dim3(256, 3), dim3(256), 0, stream>>>(qb, kb, vb, wqt, wkt, wvt, qh, kh, vt);
    k_attn<<<dim3(32, 8, 2), dim3(256), 0, stream>>>(qh, kh, vt, mfrag, po, pl);
    k_amerge<<<dim3(2048), dim3(256), 0, stream>>>(po, pl, ao);
    k_out<<<dim3(256, 2), dim3(512), 0, stream>>>(ao, wot, xp0, xp1);
    k_ln<<<dim3(4096), dim3(256), 0, stream>>>(xp0, xp1, k_in, b_o, gamma, beta, out);
}

// Round 7
// 290.557 us; speedup vs baseline: 1.0631x; 1.0631x over previous
//
#include <hip/hip_runtime.h>
#include <math.h>

// ---------- types ----------
typedef __bf16 bf16_t;
typedef bf16_t bf16x8 __attribute__((ext_vector_type(8)));
typedef float  f32x4  __attribute__((ext_vector_type(4)));
typedef unsigned short u16;
typedef u16 ushortx4 __attribute__((ext_vector_type(4)));
typedef unsigned long long u64;

#define MFMA16(a, b, c) __builtin_amdgcn_mfma_f32_16x16x32_bf16((a), (b), (c), 0, 0, 0)

__device__ __forceinline__ u16 f2bf(float f) {
    unsigned int u = __float_as_uint(f);
    u = (u + 0x7fffu + ((u >> 16) & 1u)) >> 16;
    return (u16)u;
}

__device__ __forceinline__ float bf2f(unsigned int u) {
    return __uint_as_float(u << 16);
}

// async global->LDS, 16B per lane; lds dest = wave-uniform base + lane*16
__device__ __forceinline__ void gld16(const u16* g, u16* l) {
    __builtin_amdgcn_global_load_lds(
        (const __attribute__((address_space(1))) void*)g,
        (__attribute__((address_space(3))) void*)l, 16, 0, 0);
}

// B=2, L=2048, D_MODEL=1024, H=16, DH=64, HB=32
// ws map (MB):  [phase-aware reuse]
//  qb 0-8, kb 8-16, vb 16-24        (dead after k_proj)
//  wqt 24-26 wkt 26-28 wvt 28-30    (dead after k_proj)
//  wot 30-32                        (alive until k_out)
//  qh 32-40 (scaled by log2e/8), kh 40-48, vt 48-56 (dead after k_attn)
//  ao 56-64                          (alive until k_out)
//  mfrag 64-65                       (dead after k_attn)
//  po 0-16 (over qb/kb), pl 16-17 (over vb)   [k_attn out, dead after k_amerge]
//  xp0 32-48 (over qh/kh), xp1 64-80 (over mfrag)  [k_out partials -> k_ln]
//
// K-row permutation pi (within each 64-row K tile), applied at k_attn staging:
//   M-position m = [t1 t0 q1 q0 r1 r0] holds K-row pi(m) = [t1 q1 q0 t0 r1 r0].
// Score-MFMA slot (t, quad, r) then carries k = (t>>1)*32 + quad*8 + (t&1)*4 + r,
// so each lane's 16 P values are exactly its two 8-wide PV A-fragment slices:
// P routing is pure intra-lane register packing (verified round 3).
//
// mfrag: fragment-ordered mask words (verified round 5). Word
// W = ((b*64+qbi)*32 + ktile)*32 + hfo*16 + (t*4+r); bit L=(quad*16+l15) of W =
//   mask[b][qbi*32 + hfo*16 + l15][ktile*64 + quad*8 + (t>>1)*32 + (t&1)*4 + r]
// k_attn applies each word with ONE v_cndmask_b32 from an SGPR pair.
//
// Round 7: revert r6's 64-row/wave (occupancy collapse). r5 structure + epilogue
// scratch aliased into Ks[0] (dead after final barrier): LDS 40960 -> 32768 B
// => 5 blocks/CU capacity, grid's 4 blocks/CU fully co-resident, no tail.

// ---------- fused: fp32->bf16 cvt for q,k,v + pi-ordered mask ballots + weight transposes ----------
__global__ __launch_bounds__(256) void k_prep(const float* __restrict__ q,
                                              const float* __restrict__ k,
                                              const float* __restrict__ v,
                                              const int* __restrict__ mask,
                                              const float* __restrict__ w_q,
                                              const float* __restrict__ w_k,
                                              const float* __restrict__ w_v,
                                              const float* __restrict__ w_o,
                                              u16* __restrict__ qb,
                                              u16* __restrict__ kb,
                                              u16* __restrict__ vb,
                                              u64* __restrict__ mfrag,
                                              u16* __restrict__ wqt,
                                              u16* __restrict__ wkt,
                                              u16* __restrict__ wvt,
                                              u16* __restrict__ wot) {
    __shared__ float tile[32][33];
    int bid = blockIdx.x;
    if (bid < 12288) {
        int sel = bid >> 12;                 // 0..2
        int i = (bid & 4095) * 256 + threadIdx.x;
        const float* src = sel == 0 ? q : (sel == 1 ? k : v);
        u16* dst = sel == 0 ? qb : (sel == 1 ? kb : vb);
        float4 val = ((const float4*)src)[i];
        ushortx4 r;
        r[0] = f2bf(val.x); r[1] = f2bf(val.y); r[2] = f2bf(val.z); r[3] = f2bf(val.w);
        ((ushortx4*)dst)[i] = r;
    } else if (bid < 14336) {
        // pi-ordered fragment mask ballots (see header comment)
        int wave = threadIdx.x >> 6, lane = threadIdx.x & 63;
        int l15 = lane & 15, quad = lane >> 4;
        int wt = (bid - 12288) * 4 + wave;   // [0, 8192)
        int hf = wt & 1;
        int g = wt >> 1;                     // (b*64+qbi)*32 + ktile
        int ktile = g & 31, qbi = (g >> 5) & 63, b = g >> 11;
        int qq = qbi * 32 + hf * 16 + l15;
        const int* mrow = mask + ((size_t)(b * 2048 + qq)) * 2048 + ktile * 64 + quad * 8;
        u64 myw = 0;
#pragma unroll
        for (int t = 0; t < 4; ++t)
#pragma unroll
            for (int r = 0; r < 4; ++r) {
                int m = mrow[(t >> 1) * 32 + (t & 1) * 4 + r];
                u64 bal = __ballot(m != 0);
                if (lane == t * 4 + r) myw = bal;
            }
        if (lane < 16) mfrag[(size_t)g * 32 + hf * 16 + lane] = myw;
    } else {
        int b3 = bid - 14336;
        const float* src;
        u16* dst;
        int r0, c0, C;
        if (b3 < 3072) {
            int x = b3 & 31, y = (b3 >> 5) & 1, z = b3 >> 6;
            int h = z & 15, sel = z >> 4;
            src = (sel == 0 ? w_q : (sel == 1 ? w_k : w_v)) + (size_t)h * 65536;
            dst = (sel == 0 ? wqt : (sel == 1 ? wkt : wvt)) + (size_t)h * 65536;
            r0 = x * 32; c0 = y * 32; C = 64;
        } else {
            int t = b3 - 3072;
            r0 = (t & 31) * 32; c0 = (t >> 5) * 32; C = 1024;
            src = w_o; dst = wot;
        }
        int tx = threadIdx.x & 31, ty = threadIdx.x >> 5;
        const float* s = src + ((size_t)r0) * C + c0;
#pragma unroll
        for (int i = 0; i < 4; ++i) tile[ty + i * 8][tx] = s[(ty + i * 8) * (size_t)C + tx];
        __syncthreads();
        u16* d = dst + ((size_t)c0) * 1024 + r0;
#pragma unroll
        for (int i = 0; i < 4; ++i) d[(ty + i * 8) * 1024 + tx] = f2bf(tile[tx][ty + i * 8]);
    }
}

// ---------- GEMM core body (uses As, Bs u16* into shared) ----------
#define GEMM_CORE(Ablk, Bblk, ACC)                                                    \
    int c0 = wave * 2;                                                                \
    const u16* Ag0 = Ablk + (size_t)(c0 * 16 + l15) * 1024 + quad * 8;                \
    const u16* Ag1 = Ablk + (size_t)((c0 + 1) * 16 + l15) * 1024 + quad * 8;          \
    const u16* Bg0 = Bblk + (size_t)(c0 * 16 + l15) * 1024 + quad * 8;                \
    const u16* Bg1 = Bblk + (size_t)((c0 + 1) * 16 + l15) * 1024 + quad * 8;          \
    gld16(Ag0, As + c0 * 512); gld16(Ag1, As + (c0 + 1) * 512);                       \
    gld16(Bg0, Bs + c0 * 512); gld16(Bg1, Bs + (c0 + 1) * 512);                       \
    __syncthreads();                                                                  \
    int buf = 0;                                                                      \
    for (int ks = 0; ks < 32; ++ks) {                                                 \
        if (ks < 31) {                                                                \
            int k0 = (ks + 1) * 32;                                                   \
            gld16(Ag0 + k0, As + (buf ^ 1) * 4096 + c0 * 512);                        \
            gld16(Ag1 + k0, As + (buf ^ 1) * 4096 + (c0 + 1) * 512);                  \
            gld16(Bg0 + k0, Bs + (buf ^ 1) * 4096 + c0 * 512);                        \
            gld16(Bg1 + k0, Bs + (buf ^ 1) * 4096 + (c0 + 1) * 512);                  \
        }                                                                             \
        bf16x8 af[4], bfr[4];                                                         \
        _Pragma("unroll")                                                             \
        for (int i = 0; i < 4; ++i)                                                   \
            af[i] = *(const bf16x8*)(As + buf * 4096 + (wy * 4 + i) * 512 + lane * 8);\
        _Pragma("unroll")                                                             \
        for (int j = 0; j < 4; ++j)                                                   \
            bfr[j] = *(const bf16x8*)(Bs + buf * 4096 + (wx * 4 + j) * 512 + lane * 8);\
        _Pragma("unroll")                                                             \
        for (int i = 0; i < 4; ++i)                                                   \
            _Pragma("unroll")                                                         \
            for (int j = 0; j < 4; ++j) ACC[i][j] = MFMA16(af[i], bfr[j], ACC[i][j]); \
        __syncthreads();                                                              \
        buf ^= 1;                                                                     \
    }

// ---------- fused q/k/v projections, XCD-local A-tile reuse ----------
__global__ __launch_bounds__(256) void k_proj(
    const u16* __restrict__ qb, const u16* __restrict__ kb, const u16* __restrict__ vb,
    const u16* __restrict__ wqt, const u16* __restrict__ wkt, const u16* __restrict__ wvt,
    u16* __restrict__ oq, u16* __restrict__ okh, u16* __restrict__ ovt) {
    __shared__ __align__(16) u16 smem[18432];
    u16* As = smem;
    u16* Bs = smem + 8192;
    int z = blockIdx.y, gx = blockIdx.x;
    int bm, bn;
    const u16 *A, *B;
    // fastest-varying index = tile of the LARGE matrix -> its readers co-locate per XCD
    if (z == 0)      { bm = gx & 31; bn = gx >> 5; A = qb; B = wqt; }
    else if (z == 1) { bm = gx & 31; bn = gx >> 5; A = kb; B = wkt; }
    else             { bn = gx & 31; bm = gx >> 5; A = wvt; B = vb; }
    A += (size_t)bm * 128 * 1024;
    B += (size_t)bn * 128 * 1024;
    int tid = threadIdx.x, wave = tid >> 6, lane = tid & 63;
    int wy = wave >> 1, wx = wave & 1, l15 = lane & 15, quad = lane >> 4;
    f32x4 acc[4][4] = {};
    GEMM_CORE(A, B, acc)
    u16* ep = smem + wave * 4608;
    float mulf = (z == 0) ? 0.18033688011112042f : 1.0f;
#pragma unroll
    for (int i = 0; i < 4; ++i)
#pragma unroll
        for (int j = 0; j < 4; ++j)
#pragma unroll
            for (int r = 0; r < 4; ++r)
                ep[(i * 16 + quad * 4 + r) * 72 + j * 16 + l15] = f2bf(acc[i][j][r] * mulf);
    int rl = lane >> 3, cg = lane & 7;
    if (z < 2) {
        int hh = bn * 2 + wx;
        int m0 = bm * 128 + wy * 64;
        int bb = m0 >> 11, l0 = m0 & 2047;
        u16* O = (z ? okh : oq) + ((size_t)((hh * 2 + bb) * 2048 + l0)) * 64;
#pragma unroll
        for (int s = 0; s < 8; ++s) {
            int row = s * 8 + rl;
            uint4 v = *(const uint4*)(ep + row * 72 + cg * 8);
            *(uint4*)(O + (size_t)row * 64 + cg * 8) = v;
        }
    } else {
        int m0 = bm * 128 + wy * 64;
        int hh = m0 >> 6;
        int n0 = bn * 128 + wx * 64;
        int bb = n0 >> 11, l0 = n0 & 2047;
        u16* O = ovt + (size_t)(hh * 2 + bb) * 131072 + (size_t)(m0 & 63) * 2048 + l0;
#pragma unroll
        for (int s = 0; s < 8; ++s) {
            int row = s * 8 + rl;
            uint4 v = *(const uint4*)(ep + row * 72 + cg * 8);
            *(uint4*)(O + (size_t)row * 2048 + cg * 8) = v;
        }
    }
}

// ---------- flash attention: split-K=2, hb-fastest grid (XCD-local K/V) ----------
// grid (32 hb, 16 qt, 2 ks); 256 thr = 4 waves x 32 Q-rows
// pi-permuted K staging (r3) -> P in registers; mfrag SGPR-cndmask mask (r5).
// Epilogue scratch aliased into Ks[0] (dead after final barrier): LDS 32 KB.
__global__ __launch_bounds__(256) void k_attn(
    const u16* __restrict__ qh, const u16* __restrict__ kh,
    const u16* __restrict__ vt, const u64* __restrict__ mfrag,
    u16* __restrict__ po, float* __restrict__ pl) {
    int hb = blockIdx.x, qt = blockIdx.y, ksp = blockIdx.z;
    int b = hb & 1;
    int tid = threadIdx.x, wave = tid >> 6, lane = tid & 63;
    int l15 = lane & 15, quad = lane >> 4;

    __shared__ __align__(16) u16 Ks[2][4096], Vs[2][4096];

    int qrow0 = qt * 128 + wave * 32;
    const u16* Qp = qh + ((size_t)(hb * 2048) + qrow0 + l15) * 64 + quad * 8;
    bf16x8 qf[2][2];
    qf[0][0] = *(const bf16x8*)Qp;
    qf[0][1] = *(const bf16x8*)(Qp + 32);
    qf[1][0] = *(const bf16x8*)(Qp + 1024);
    qf[1][1] = *(const bf16x8*)(Qp + 1024 + 32);

    int c0 = wave * 2;
    // pi-permuted K-row for this staging lane: [w1 l3 l2 w0 l1 l0]
    int rowp = (wave >> 1) * 32 + (l15 >> 2) * 8 + (wave & 1) * 4 + (l15 & 3);
    const u16* Kg0 = kh + (size_t)hb * 131072 + (size_t)ksp * 65536 +
                     (size_t)rowp * 64 + quad * 8;
    const u16* Kg1 = Kg0 + 32;
    const u16* Vg0 = vt + (size_t)hb * 131072 + (size_t)(wave * 16 + l15) * 2048 +
                     ksp * 1024 + quad * 8;
    const u16* Vg1 = Vg0 + 32;

    // wave-uniform mask-word pointer in constant addrspace -> s_load (SALU pipe)
    int wu = __builtin_amdgcn_readfirstlane(wave);
    const __attribute__((address_space(4))) u64* Mw =
        (const __attribute__((address_space(4))) u64*)(mfrag +
            (size_t)(((b * 64 + qt * 4 + wu) * 32 + ksp * 16) * 32));

    float l_lane[2] = {0.f, 0.f};
    f32x4 o[2][4] = {};
    float neg = -3e30f;

    gld16(Kg0, &Ks[0][c0 * 512]);
    gld16(Kg1, &Ks[0][(c0 + 1) * 512]);
    gld16(Vg0, &Vs[0][c0 * 512]);
    gld16(Vg1, &Vs[0][(c0 + 1) * 512]);
    __syncthreads();
    int buf = 0;
    for (int kt = 0; kt < 16; ++kt) {
        if (kt < 15) {
            gld16(Kg0 + (size_t)(kt + 1) * 4096, &Ks[buf ^ 1][c0 * 512]);
            gld16(Kg1 + (size_t)(kt + 1) * 4096, &Ks[buf ^ 1][(c0 + 1) * 512]);
            gld16(Vg0 + (size_t)(kt + 1) * 64, &Vs[buf ^ 1][c0 * 512]);
            gld16(Vg1 + (size_t)(kt + 1) * 64, &Vs[buf ^ 1][(c0 + 1) * 512]);
        }
        bf16x8 kf[8], vf[8];
#pragma unroll
        for (int c = 0; c < 8; ++c) kf[c] = *(const bf16x8*)&Ks[buf][c * 512 + lane * 8];
#pragma unroll
        for (int c = 0; c < 8; ++c) vf[c] = *(const bf16x8*)&Vs[buf][c * 512 + lane * 8];
#pragma unroll
        for (int hf = 0; hf < 2; ++hf) {
            u64 mw[16];
#pragma unroll
            for (int i = 0; i < 16; ++i) mw[i] = Mw[kt * 32 + hf * 16 + i];
            f32x4 st[4] = {};
#pragma unroll
            for (int t = 0; t < 4; ++t) {
                st[t] = MFMA16(kf[t * 2], qf[hf][0], st[t]);
                st[t] = MFMA16(kf[t * 2 + 1], qf[hf][1], st[t]);
            }
            // one cndmask per element: bit[lane] of mfrag word (t*4+r) selects -3e30
            float p[16];
#pragma unroll
            for (int t = 0; t < 4; ++t)
#pragma unroll
                for (int r = 0; r < 4; ++r) {
                    float sc;
                    asm("v_cndmask_b32 %0, %1, %2, %3"
                        : "=v"(sc)
                        : "v"(st[t][r]), "v"(neg), "s"(mw[t * 4 + r]));
                    p[t * 4 + r] = __builtin_amdgcn_exp2f(sc);
                }
            // exp2 + verified manual bf16 pack, direct into PV A-fragments
            float ll = 0.f;
            unsigned int pw[8];
#pragma unroll
            for (int t = 0; t < 4; ++t) {
                float p0 = p[t * 4 + 0], p1 = p[t * 4 + 1];
                float p2 = p[t * 4 + 2], p3 = p[t * 4 + 3];
                ll += (p0 + p1) + (p2 + p3);
                pw[t * 2]     = (__float_as_uint(p1) & 0xffff0000u) | (__float_as_uint(p0) >> 16);
                pw[t * 2 + 1] = (__float_as_uint(p3) & 0xffff0000u) | (__float_as_uint(p2) >> 16);
            }
            l_lane[hf] += ll;
            union { unsigned int w[4]; bf16x8 v; } p0u, p1u;
            p0u.w[0] = pw[0]; p0u.w[1] = pw[1]; p0u.w[2] = pw[2]; p0u.w[3] = pw[3];
            p1u.w[0] = pw[4]; p1u.w[1] = pw[5]; p1u.w[2] = pw[6]; p1u.w[3] = pw[7];
#pragma unroll
            for (int t = 0; t < 4; ++t) {
                o[hf][t] = MFMA16(p0u.v, vf[t * 2], o[hf][t]);
                o[hf][t] = MFMA16(p1u.v, vf[t * 2 + 1], o[hf][t]);
            }
        }
        __syncthreads();
        buf ^= 1;
    }
    // ---- store partial l + unnormalized partial O (coalesced via swizzled scratch) ----
    // Ks is dead after the final barrier above; each wave uses its own 2 KB slice.
    size_t rowbase = ((size_t)ksp * 32 + hb) * 2048 + qrow0;
    int rl = lane >> 3, cg = lane & 7;
    u16* eb = &Ks[0][0] + wave * 1024;
#pragma unroll
    for (int hf = 0; hf < 2; ++hf) {
        float ls = l_lane[hf];
        ls += __shfl_xor(ls, 16, 64);
        ls += __shfl_xor(ls, 32, 64);
        if (quad == 0) pl[rowbase + hf * 16 + l15] = ls;
#pragma unroll
        for (int t = 0; t < 4; ++t)
#pragma unroll
            for (int r = 0; r < 4; ++r) {
                int row = quad * 4 + r, col = t * 16 + l15;
                int g = col >> 3;
                eb[row * 64 + ((g ^ (row & 7)) << 3) + (col & 7)] =
                    f2bf(o[hf][t][r]);
            }
#pragma unroll
        for (int s = 0; s < 2; ++s) {
            int row = s * 8 + rl;
            uint4 v = *(const uint4*)&eb[row * 64 + ((cg ^ (row & 7)) << 3)];
            *(uint4*)(po + (rowbase + hf * 16 + row) * 64 + cg * 8) = v;
        }
    }
}

// ---------- split-K merge: ao = (po0+po1)/(l0+l1) ----------
__global__ __launch_bounds__(256) void k_amerge(const u16* __restrict__ po,
                                                const float* __restrict__ pl,
                                                u16* __restrict__ ao) {
    int bid = blockIdx.x;               // 32 hb x 64 row-chunks
    int hb = bid >> 6, rc = bid & 63;
    int h = hb >> 1, b = hb & 1;
    int tid = threadIdx.x;
    int r = tid >> 3, c = tid & 7;
    int row = rc * 32 + r;
    size_t i0 = ((size_t)hb * 2048 + row) * 64 + c * 8;
    uint4 a0 = *(const uint4*)(po + i0);
    uint4 a1 = *(const uint4*)(po + i0 + 4194304);
    float l0 = pl[(size_t)hb * 2048 + row];
    float l1 = pl[65536 + (size_t)hb * 2048 + row];
    float inv = 1.0f / (l0 + l1);
    unsigned int* pa0 = (unsigned int*)&a0;
    unsigned int* pa1 = (unsigned int*)&a1;
    uint4 out;
    unsigned int* po_ = (unsigned int*)&out;
#pragma unroll
    for (int i = 0; i < 4; ++i) {
        float lo = (bf2f(pa0[i] & 0xffffu) + bf2f(pa1[i] & 0xffffu)) * inv;
        float hi = (bf2f(pa0[i] >> 16) + bf2f(pa1[i] >> 16)) * inv;
        po_[i] = (unsigned int)f2bf(lo) | ((unsigned int)f2bf(hi) << 16);
    }
    *(uint4*)(ao + ((size_t)(b * 2048 + row)) * 1024 + h * 64 + c * 8) = out;
}

// ---------- output projection, split-K=2, raw fp32 partials, bm-fastest ----------
__global__ __launch_bounds__(512) void k_out(
    const u16* __restrict__ ao, const u16* __restrict__ wot,
    float* __restrict__ xp0, float* __restrict__ xp1) {
    __shared__ __align__(16) u16 smem[18432];
    u16* As = smem;
    u16* Bs = smem + 8192;
    int gx = blockIdx.x, bm = gx & 31, bn = gx >> 5;
    int ksp = blockIdx.y;
    const u16* A = ao + (size_t)bm * 128 * 1024 + ksp * 512;
    const u16* B = wot + (size_t)bn * 128 * 1024 + ksp * 512;
    float* xp = ksp ? xp1 : xp0;
    int tid = threadIdx.x, wave = tid >> 6, lane = tid & 63;
    int wy = wave >> 2, wx = wave & 3, l15 = lane & 15, quad = lane >> 4;
    const u16* Ag = A + (size_t)(wave * 16 + l15) * 1024 + quad * 8;
    const u16* Bg = B + (size_t)(wave * 16 + l15) * 1024 + quad * 8;
    f32x4 acc[4][2] = {};
    gld16(Ag, As + wave * 512);
    gld16(Bg, Bs + wave * 512);
    __syncthreads();
    int buf = 0;
    for (int ks = 0; ks < 16; ++ks) {
        if (ks < 15) {
            int k0 = (ks + 1) * 32;
            gld16(Ag + k0, As + (buf ^ 1) * 4096 + wave * 512);
            gld16(Bg + k0, Bs + (buf ^ 1) * 4096 + wave * 512);
        }
        bf16x8 af[4], bfr[2];
#pragma unroll
        for (int i = 0; i < 4; ++i)
            af[i] = *(const bf16x8*)(As + buf * 4096 + (wy * 4 + i) * 512 + lane * 8);
#pragma unroll
        for (int j = 0; j < 2; ++j)
            bfr[j] = *(const bf16x8*)(Bs + buf * 4096 + (wx * 2 + j) * 512 + lane * 8);
#pragma unroll
        for (int i = 0; i < 4; ++i)
#pragma unroll
            for (int j = 0; j < 2; ++j) acc[i][j] = MFMA16(af[i], bfr[j], acc[i][j]);
        __syncthreads();
        buf ^= 1;
    }
    float* epf = (float*)smem + wave * 1152;
    int rl = lane >> 3, cg = lane & 7;
    int mbase = bm * 128 + wy * 64, nbase = bn * 128 + wx * 32;
#pragma unroll
    for (int cc = 0; cc < 2; ++cc) {
#pragma unroll
        for (int i2 = 0; i2 < 2; ++i2)
#pragma unroll
            for (int j = 0; j < 2; ++j)
#pragma unroll
                for (int r = 0; r < 4; ++r)
                    epf[(i2 * 16 + quad * 4 + r) * 36 + j * 16 + l15] =
                        acc[cc * 2 + i2][j][r];
#pragma unroll
        for (int s = 0; s < 4; ++s) {
            int row = s * 8 + rl;
            f32x4 v = *(const f32x4*)(epf + row * 36 + cg * 4);
            int m = mbase + cc * 32 + row, n = nbase + cg * 4;
            *(f32x4*)(xp + (size_t)m * 1024 + n) = v;
        }
    }
}

// ---------- layernorm + split-K sum + bias + residual ----------
__global__ __launch_bounds__(256) void k_ln(const float* __restrict__ xp0,
                                            const float* __restrict__ xp1,
                                            const float* __restrict__ resid,
                                            const float* __restrict__ bo,
                                            const float* __restrict__ gamma,
                                            const float* __restrict__ beta,
                                            float* __restrict__ out) {
    int row = blockIdx.x;
    size_t base = (size_t)row * 256;
    float4 a0 = ((const float4*)xp0)[base + threadIdx.x];
    float4 a1 = ((const float4*)xp1)[base + threadIdx.x];
    float4 rs = ((const float4*)resid)[base + threadIdx.x];
    float4 b4 = ((const float4*)bo)[threadIdx.x];
    float4 v;
    v.x = a0.x + a1.x + rs.x + b4.x;
    v.y = a0.y + a1.y + rs.y + b4.y;
    v.z = a0.z + a1.z + rs.z + b4.z;
    v.w = a0.w + a1.w + rs.w + b4.w;
    float s = v.x + v.y + v.z + v.w;
    float ss = v.x * v.x + v.y * v.y + v.z * v.z + v.w * v.w;
#pragma unroll
    for (int off = 32; off; off >>= 1) {
        s += __shfl_down(s, off, 64);
        ss += __shfl_down(ss, off, 64);
    }
    __shared__ float sb[8];
    int wave = threadIdx.x >> 6, lane = threadIdx.x & 63;
    if (lane == 0) { sb[wave] = s; sb[4 + wave] = ss; }
    __syncthreads();
    s = sb[0] + sb[1] + sb[2] + sb[3];
    ss = sb[4] + sb[5] + sb[6] + sb[7];
    float mean = s * (1.0f / 1024.0f);
    float var = fmaxf((ss - 1024.0f * mean * mean) * (1.0f / 1023.0f), 0.f);
    float inv = 1.0f / (sqrtf(var) + 1e-3f);
    float4 g = ((const float4*)gamma)[threadIdx.x];
    float4 bt = ((const float4*)beta)[threadIdx.x];
    float4 o;
    o.x = (v.x - mean) * inv * g.x + bt.x;
    o.y = (v.y - mean) * inv * g.y + bt.y;
    o.z = (v.z - mean) * inv * g.z + bt.z;
    o.w = (v.w - mean) * inv * g.w + bt.w;
    ((float4*)(out))[base + threadIdx.x] = o;
}

// ---------- launch ----------
extern "C" void kernel_launch(void* const* d_in, const int* in_sizes, int n_in,
                              void* d_out, int out_size, void* d_ws, size_t ws_size,
                              hipStream_t stream) {
    const float* v_in  = (const float*)d_in[0];
    const float* k_in  = (const float*)d_in[1];
    const float* q_in  = (const float*)d_in[2];
    const int*   mask  = (const int*)d_in[3];
    const float* w_q   = (const float*)d_in[4];
    const float* w_k   = (const float*)d_in[5];
    const float* w_v   = (const float*)d_in[6];
    const float* w_o   = (const float*)d_in[7];
    const float* b_o   = (const float*)d_in[8];
    const float* gamma = (const float*)d_in[9];
    const float* beta  = (const float*)d_in[10];
    float* out = (float*)d_out;

    char* ws = (char*)d_ws;
    const size_t MB = 1ull << 20;
    u16* qb  = (u16*)(ws + 0 * MB);
    u16* kb  = (u16*)(ws + 8 * MB);
    u16* vb  = (u16*)(ws + 16 * MB);
    u16* wqt = (u16*)(ws + 24 * MB);
    u16* wkt = (u16*)(ws + 26 * MB);
    u16* wvt = (u16*)(ws + 28 * MB);
    u16* wot = (u16*)(ws + 30 * MB);
    u16* qh  = (u16*)(ws + 32 * MB);
    u16* kh  = (u16*)(ws + 40 * MB);
    u16* vt  = (u16*)(ws + 48 * MB);
    u16* ao  = (u16*)(ws + 56 * MB);
    u64* mfrag = (u64*)(ws + 64 * MB);
    u16*   po = (u16*)(ws + 0 * MB);     // over qb/kb (dead after k_proj)
    float* pl = (float*)(ws + 16 * MB);  // over vb (dead after k_proj)
    float* xp0 = (float*)(ws + 32 * MB); // over qh/kh (dead after k_attn)
    float* xp1 = (float*)(ws + 64 * MB); // over mfrag (dead after k_attn)

    k_prep<<<dim3(18432), dim3(256), 0, stream>>>(q_in, k_in, v_in, mask,
                                                  w_q, w_k, w_v, w_o,
                                                  qb, kb, vb, mfrag,
                                                  wqt, wkt, wvt, wot);
    k_proj<<<dim3(256, 3), dim3(256), 0, stream>>>(qb, kb, vb, wqt, wkt, wvt, qh, kh, vt);
    k_attn<<<dim3(32, 16, 2), dim3(256), 0, stream>>>(qh, kh, vt, mfrag, po, pl);
    k_amerge<<<dim3(2048), dim3(256), 0, stream>>>(po, pl, ao);
    k_out<<<dim3(256, 2), dim3(512), 0, stream>>>(ao, wot, xp0, xp1);
    k_ln<<<dim3(4096), dim3(256), 0, stream>>>(xp0, xp1, k_in, b_o, gamma, beta, out);
}

// Round 9
// 290.019 us; speedup vs baseline: 1.0651x; 1.0019x over previous
//
#include <hip/hip_runtime.h>
#include <math.h>

// ---------- types ----------
typedef __bf16 bf16_t;
typedef bf16_t bf16x8 __attribute__((ext_vector_type(8)));
typedef float  f32x4  __attribute__((ext_vector_type(4)));
typedef unsigned short u16;
typedef u16 ushortx4 __attribute__((ext_vector_type(4)));
typedef unsigned long long u64;

#define MFMA16(a, b, c) __builtin_amdgcn_mfma_f32_16x16x32_bf16((a), (b), (c), 0, 0, 0)

__device__ __forceinline__ u16 f2bf(float f) {
    unsigned int u = __float_as_uint(f);
    u = (u + 0x7fffu + ((u >> 16) & 1u)) >> 16;
    return (u16)u;
}

__device__ __forceinline__ float bf2f(unsigned int u) {
    return __uint_as_float(u << 16);
}

// async global->LDS, 16B per lane; lds dest = wave-uniform base + lane*16
__device__ __forceinline__ void gld16(const u16* g, u16* l) {
    __builtin_amdgcn_global_load_lds(
        (const __attribute__((address_space(1))) void*)g,
        (__attribute__((address_space(3))) void*)l, 16, 0, 0);
}

// B=2, L=2048, D_MODEL=1024, H=16, DH=64, HB=32
// ws map (MB):  [phase-aware reuse]
//  qb 0-8, kb 8-16, vb 16-24        (dead after k_proj)
//  wqt 24-26 wkt 26-28 wvt 28-30    (dead after k_proj)
//  wot 30-32                        (alive until k_out)
//  qh 32-40 (scaled by log2e/8), kh 40-48, vt 48-56 (dead after k_attn)
//  ao 56-64                          (alive until k_out)
//  mfrag 64-65                       (dead after k_attn)
//  po 0-16 (over qb/kb), pl 16-17 (over vb)   [k_attn out, dead after k_amerge]
//  xp0 32-48 (over qh/kh), xp1 64-80 (over mfrag)  [k_out partials -> k_ln]
//
// K-row permutation pi (within each 64-row K tile), applied at k_attn staging:
//   M-position m = [t1 t0 q1 q0 r1 r0] holds K-row pi(m) = [t1 q1 q0 t0 r1 r0].
// Score-MFMA slot (t, quad, r) then carries k = (t>>1)*32 + quad*8 + (t&1)*4 + r,
// so each lane's 16 P values are exactly its two 8-wide PV A-fragment slices:
// P routing is pure intra-lane register packing (verified round 3).
//
// mfrag: fragment-ordered mask words (verified round 5). Word
// W = ((b*64+qbi)*32 + ktile)*32 + hfo*16 + (t*4+r); bit L=(quad*16+l15) of W =
//   mask[b][qbi*32 + hfo*16 + l15][ktile*64 + quad*8 + (t>>1)*32 + (t&1)*4 + r]
// k_attn applies each word with ONE v_cndmask_b32 from an SGPR pair.
//
// Round 9: r5 verified base. ONE change: P f32->bf16 via compiler casts
// (hand-asm v_cvt_pk_bf16_f32 FAILED r8 — its packing semantics differ from
// assumption; r1/r2 failures now attributed to it). Compiler knows the true
// instruction semantics and emits the efficient pk form itself (m240).

// ---------- fused: fp32->bf16 cvt for q,k,v + pi-ordered mask ballots + weight transposes ----------
__global__ __launch_bounds__(256) void k_prep(const float* __restrict__ q,
                                              const float* __restrict__ k,
                                              const float* __restrict__ v,
                                              const int* __restrict__ mask,
                                              const float* __restrict__ w_q,
                                              const float* __restrict__ w_k,
                                              const float* __restrict__ w_v,
                                              const float* __restrict__ w_o,
                                              u16* __restrict__ qb,
                                              u16* __restrict__ kb,
                                              u16* __restrict__ vb,
                                              u64* __restrict__ mfrag,
                                              u16* __restrict__ wqt,
                                              u16* __restrict__ wkt,
                                              u16* __restrict__ wvt,
                                              u16* __restrict__ wot) {
    __shared__ float tile[32][33];
    int bid = blockIdx.x;
    if (bid < 12288) {
        int sel = bid >> 12;                 // 0..2
        int i = (bid & 4095) * 256 + threadIdx.x;
        const float* src = sel == 0 ? q : (sel == 1 ? k : v);
        u16* dst = sel == 0 ? qb : (sel == 1 ? kb : vb);
        float4 val = ((const float4*)src)[i];
        ushortx4 r;
        r[0] = f2bf(val.x); r[1] = f2bf(val.y); r[2] = f2bf(val.z); r[3] = f2bf(val.w);
        ((ushortx4*)dst)[i] = r;
    } else if (bid < 14336) {
        // pi-ordered fragment mask ballots (see header comment)
        int wave = threadIdx.x >> 6, lane = threadIdx.x & 63;
        int l15 = lane & 15, quad = lane >> 4;
        int wt = (bid - 12288) * 4 + wave;   // [0, 8192)
        int hf = wt & 1;
        int g = wt >> 1;                     // (b*64+qbi)*32 + ktile
        int ktile = g & 31, qbi = (g >> 5) & 63, b = g >> 11;
        int qq = qbi * 32 + hf * 16 + l15;
        const int* mrow = mask + ((size_t)(b * 2048 + qq)) * 2048 + ktile * 64 + quad * 8;
        u64 myw = 0;
#pragma unroll
        for (int t = 0; t < 4; ++t)
#pragma unroll
            for (int r = 0; r < 4; ++r) {
                int m = mrow[(t >> 1) * 32 + (t & 1) * 4 + r];
                u64 bal = __ballot(m != 0);
                if (lane == t * 4 + r) myw = bal;
            }
        if (lane < 16) mfrag[(size_t)g * 32 + hf * 16 + lane] = myw;
    } else {
        int b3 = bid - 14336;
        const float* src;
        u16* dst;
        int r0, c0, C;
        if (b3 < 3072) {
            int x = b3 & 31, y = (b3 >> 5) & 1, z = b3 >> 6;
            int h = z & 15, sel = z >> 4;
            src = (sel == 0 ? w_q : (sel == 1 ? w_k : w_v)) + (size_t)h * 65536;
            dst = (sel == 0 ? wqt : (sel == 1 ? wkt : wvt)) + (size_t)h * 65536;
            r0 = x * 32; c0 = y * 32; C = 64;
        } else {
            int t = b3 - 3072;
            r0 = (t & 31) * 32; c0 = (t >> 5) * 32; C = 1024;
            src = w_o; dst = wot;
        }
        int tx = threadIdx.x & 31, ty = threadIdx.x >> 5;
        const float* s = src + ((size_t)r0) * C + c0;
#pragma unroll
        for (int i = 0; i < 4; ++i) tile[ty + i * 8][tx] = s[(ty + i * 8) * (size_t)C + tx];
        __syncthreads();
        u16* d = dst + ((size_t)c0) * 1024 + r0;
#pragma unroll
        for (int i = 0; i < 4; ++i) d[(ty + i * 8) * 1024 + tx] = f2bf(tile[tx][ty + i * 8]);
    }
}

// ---------- GEMM core body (uses As, Bs u16* into shared) ----------
#define GEMM_CORE(Ablk, Bblk, ACC)                                                    \
    int c0 = wave * 2;                                                                \
    const u16* Ag0 = Ablk + (size_t)(c0 * 16 + l15) * 1024 + quad * 8;                \
    const u16* Ag1 = Ablk + (size_t)((c0 + 1) * 16 + l15) * 1024 + quad * 8;          \
    const u16* Bg0 = Bblk + (size_t)(c0 * 16 + l15) * 1024 + quad * 8;                \
    const u16* Bg1 = Bblk + (size_t)((c0 + 1) * 16 + l15) * 1024 + quad * 8;          \
    gld16(Ag0, As + c0 * 512); gld16(Ag1, As + (c0 + 1) * 512);                       \
    gld16(Bg0, Bs + c0 * 512); gld16(Bg1, Bs + (c0 + 1) * 512);                       \
    __syncthreads();                                                                  \
    int buf = 0;                                                                      \
    for (int ks = 0; ks < 32; ++ks) {                                                 \
        if (ks < 31) {                                                                \
            int k0 = (ks + 1) * 32;                                                   \
            gld16(Ag0 + k0, As + (buf ^ 1) * 4096 + c0 * 512);                        \
            gld16(Ag1 + k0, As + (buf ^ 1) * 4096 + (c0 + 1) * 512);                  \
            gld16(Bg0 + k0, Bs + (buf ^ 1) * 4096 + c0 * 512);                        \
            gld16(Bg1 + k0, Bs + (buf ^ 1) * 4096 + (c0 + 1) * 512);                  \
        }                                                                             \
        bf16x8 af[4], bfr[4];                                                         \
        _Pragma("unroll")                                                             \
        for (int i = 0; i < 4; ++i)                                                   \
            af[i] = *(const bf16x8*)(As + buf * 4096 + (wy * 4 + i) * 512 + lane * 8);\
        _Pragma("unroll")                                                             \
        for (int j = 0; j < 4; ++j)                                                   \
            bfr[j] = *(const bf16x8*)(Bs + buf * 4096 + (wx * 4 + j) * 512 + lane * 8);\
        _Pragma("unroll")                                                             \
        for (int i = 0; i < 4; ++i)                                                   \
            _Pragma("unroll")                                                         \
            for (int j = 0; j < 4; ++j) ACC[i][j] = MFMA16(af[i], bfr[j], ACC[i][j]); \
        __syncthreads();                                                              \
        buf ^= 1;                                                                     \
    }

// ---------- fused q/k/v projections, XCD-local A-tile reuse ----------
__global__ __launch_bounds__(256) void k_proj(
    const u16* __restrict__ qb, const u16* __restrict__ kb, const u16* __restrict__ vb,
    const u16* __restrict__ wqt, const u16* __restrict__ wkt, const u16* __restrict__ wvt,
    u16* __restrict__ oq, u16* __restrict__ okh, u16* __restrict__ ovt) {
    __shared__ __align__(16) u16 smem[18432];
    u16* As = smem;
    u16* Bs = smem + 8192;
    int z = blockIdx.y, gx = blockIdx.x;
    int bm, bn;
    const u16 *A, *B;
    // fastest-varying index = tile of the LARGE matrix -> its readers co-locate per XCD
    if (z == 0)      { bm = gx & 31; bn = gx >> 5; A = qb; B = wqt; }
    else if (z == 1) { bm = gx & 31; bn = gx >> 5; A = kb; B = wkt; }
    else             { bn = gx & 31; bm = gx >> 5; A = wvt; B = vb; }
    A += (size_t)bm * 128 * 1024;
    B += (size_t)bn * 128 * 1024;
    int tid = threadIdx.x, wave = tid >> 6, lane = tid & 63;
    int wy = wave >> 1, wx = wave & 1, l15 = lane & 15, quad = lane >> 4;
    f32x4 acc[4][4] = {};
    GEMM_CORE(A, B, acc)
    u16* ep = smem + wave * 4608;
    float mulf = (z == 0) ? 0.18033688011112042f : 1.0f;
#pragma unroll
    for (int i = 0; i < 4; ++i)
#pragma unroll
        for (int j = 0; j < 4; ++j)
#pragma unroll
            for (int r = 0; r < 4; ++r)
                ep[(i * 16 + quad * 4 + r) * 72 + j * 16 + l15] = f2bf(acc[i][j][r] * mulf);
    int rl = lane >> 3, cg = lane & 7;
    if (z < 2) {
        int hh = bn * 2 + wx;
        int m0 = bm * 128 + wy * 64;
        int bb = m0 >> 11, l0 = m0 & 2047;
        u16* O = (z ? okh : oq) + ((size_t)((hh * 2 + bb) * 2048 + l0)) * 64;
#pragma unroll
        for (int s = 0; s < 8; ++s) {
            int row = s * 8 + rl;
            uint4 v = *(const uint4*)(ep + row * 72 + cg * 8);
            *(uint4*)(O + (size_t)row * 64 + cg * 8) = v;
        }
    } else {
        int m0 = bm * 128 + wy * 64;
        int hh = m0 >> 6;
        int n0 = bn * 128 + wx * 64;
        int bb = n0 >> 11, l0 = n0 & 2047;
        u16* O = ovt + (size_t)(hh * 2 + bb) * 131072 + (size_t)(m0 & 63) * 2048 + l0;
#pragma unroll
        for (int s = 0; s < 8; ++s) {
            int row = s * 8 + rl;
            uint4 v = *(const uint4*)(ep + row * 72 + cg * 8);
            *(uint4*)(O + (size_t)row * 2048 + cg * 8) = v;
        }
    }
}

// ---------- flash attention: split-K=2, hb-fastest grid (XCD-local K/V) ----------
// grid (32 hb, 16 qt, 2 ks); 256 thr = 4 waves x 32 Q-rows
// pi-permuted K staging (r3) -> P in registers; mfrag SGPR-cndmask mask (r5);
// P f32->bf16 via compiler casts (this round's single change).
__global__ __launch_bounds__(256) void k_attn(
    const u16* __restrict__ qh, const u16* __restrict__ kh,
    const u16* __restrict__ vt, const u64* __restrict__ mfrag,
    u16* __restrict__ po, float* __restrict__ pl) {
    int hb = blockIdx.x, qt = blockIdx.y, ksp = blockIdx.z;
    int b = hb & 1;
    int tid = threadIdx.x, wave = tid >> 6, lane = tid & 63;
    int l15 = lane & 15, quad = lane >> 4;

    __shared__ __align__(16) u16 Ks[2][4096], Vs[2][4096];
    __shared__ __align__(16) u16 Eb[4][1024];   // epilogue scratch (swizzled)

    int qrow0 = qt * 128 + wave * 32;
    const u16* Qp = qh + ((size_t)(hb * 2048) + qrow0 + l15) * 64 + quad * 8;
    bf16x8 qf[2][2];
    qf[0][0] = *(const bf16x8*)Qp;
    qf[0][1] = *(const bf16x8*)(Qp + 32);
    qf[1][0] = *(const bf16x8*)(Qp + 1024);
    qf[1][1] = *(const bf16x8*)(Qp + 1024 + 32);

    int c0 = wave * 2;
    // pi-permuted K-row for this staging lane: [w1 l3 l2 w0 l1 l0]
    int rowp = (wave >> 1) * 32 + (l15 >> 2) * 8 + (wave & 1) * 4 + (l15 & 3);
    const u16* Kg0 = kh + (size_t)hb * 131072 + (size_t)ksp * 65536 +
                     (size_t)rowp * 64 + quad * 8;
    const u16* Kg1 = Kg0 + 32;
    const u16* Vg0 = vt + (size_t)hb * 131072 + (size_t)(wave * 16 + l15) * 2048 +
                     ksp * 1024 + quad * 8;
    const u16* Vg1 = Vg0 + 32;

    // wave-uniform mask-word pointer in constant addrspace -> s_load (SALU pipe)
    int wu = __builtin_amdgcn_readfirstlane(wave);
    const __attribute__((address_space(4))) u64* Mw =
        (const __attribute__((address_space(4))) u64*)(mfrag +
            (size_t)(((b * 64 + qt * 4 + wu) * 32 + ksp * 16) * 32));

    float l_lane[2] = {0.f, 0.f};
    f32x4 o[2][4] = {};
    float neg = -3e30f;

    gld16(Kg0, &Ks[0][c0 * 512]);
    gld16(Kg1, &Ks[0][(c0 + 1) * 512]);
    gld16(Vg0, &Vs[0][c0 * 512]);
    gld16(Vg1, &Vs[0][(c0 + 1) * 512]);
    __syncthreads();
    int buf = 0;
    for (int kt = 0; kt < 16; ++kt) {
        if (kt < 15) {
            gld16(Kg0 + (size_t)(kt + 1) * 4096, &Ks[buf ^ 1][c0 * 512]);
            gld16(Kg1 + (size_t)(kt + 1) * 4096, &Ks[buf ^ 1][(c0 + 1) * 512]);
            gld16(Vg0 + (size_t)(kt + 1) * 64, &Vs[buf ^ 1][c0 * 512]);
            gld16(Vg1 + (size_t)(kt + 1) * 64, &Vs[buf ^ 1][(c0 + 1) * 512]);
        }
        bf16x8 kf[8], vf[8];
#pragma unroll
        for (int c = 0; c < 8; ++c) kf[c] = *(const bf16x8*)&Ks[buf][c * 512 + lane * 8];
#pragma unroll
        for (int c = 0; c < 8; ++c) vf[c] = *(const bf16x8*)&Vs[buf][c * 512 + lane * 8];
#pragma unroll
        for (int hf = 0; hf < 2; ++hf) {
            u64 mw[16];
#pragma unroll
            for (int i = 0; i < 16; ++i) mw[i] = Mw[kt * 32 + hf * 16 + i];
            f32x4 st[4] = {};
#pragma unroll
            for (int t = 0; t < 4; ++t) {
                st[t] = MFMA16(kf[t * 2], qf[hf][0], st[t]);
                st[t] = MFMA16(kf[t * 2 + 1], qf[hf][1], st[t]);
            }
            // one cndmask per element: bit[lane] of mfrag word (t*4+r) selects -3e30
            float p[16];
#pragma unroll
            for (int t = 0; t < 4; ++t)
#pragma unroll
                for (int r = 0; r < 4; ++r) {
                    float sc;
                    asm("v_cndmask_b32 %0, %1, %2, %3"
                        : "=v"(sc)
                        : "v"(st[t][r]), "v"(neg), "s"(mw[t * 4 + r]));
                    p[t * 4 + r] = __builtin_amdgcn_exp2f(sc);
                }
            float ll = ((p[0] + p[1]) + (p[2] + p[3])) + ((p[4] + p[5]) + (p[6] + p[7]))
                     + ((p[8] + p[9]) + (p[10] + p[11])) + ((p[12] + p[13]) + (p[14] + p[15]));
            l_lane[hf] += ll;
            // PV A-fragments = p[0..7] and p[8..15] in element order; let the
            // compiler pick the f32->bf16 conversion instructions (RNE).
            union { bf16_t e[8]; bf16x8 v; } p0u, p1u;
#pragma unroll
            for (int i = 0; i < 8; ++i) {
                p0u.e[i] = (bf16_t)p[i];
                p1u.e[i] = (bf16_t)p[8 + i];
            }
#pragma unroll
            for (int t = 0; t < 4; ++t) {
                o[hf][t] = MFMA16(p0u.v, vf[t * 2], o[hf][t]);
                o[hf][t] = MFMA16(p1u.v, vf[t * 2 + 1], o[hf][t]);
            }
        }
        __syncthreads();
        buf ^= 1;
    }
    // ---- store partial l + unnormalized partial O (coalesced via swizzled Eb) ----
    size_t rowbase = ((size_t)ksp * 32 + hb) * 2048 + qrow0;
    int rl = lane >> 3, cg = lane & 7;
#pragma unroll
    for (int hf = 0; hf < 2; ++hf) {
        float ls = l_lane[hf];
        ls += __shfl_xor(ls, 16, 64);
        ls += __shfl_xor(ls, 32, 64);
        if (quad == 0) pl[rowbase + hf * 16 + l15] = ls;
#pragma unroll
        for (int t = 0; t < 4; ++t)
#pragma unroll
            for (int r = 0; r < 4; ++r) {
                int row = quad * 4 + r, col = t * 16 + l15;
                int g = col >> 3;
                Eb[wave][row * 64 + ((g ^ (row & 7)) << 3) + (col & 7)] =
                    f2bf(o[hf][t][r]);
            }
#pragma unroll
        for (int s = 0; s < 2; ++s) {
            int row = s * 8 + rl;
            uint4 v = *(const uint4*)&Eb[wave][row * 64 + ((cg ^ (row & 7)) << 3)];
            *(uint4*)(po + (rowbase + hf * 16 + row) * 64 + cg * 8) = v;
        }
    }
}

// ---------- split-K merge: ao = (po0+po1)/(l0+l1) ----------
__global__ __launch_bounds__(256) void k_amerge(const u16* __restrict__ po,
                                                const float* __restrict__ pl,
                                                u16* __restrict__ ao) {
    int bid = blockIdx.x;               // 32 hb x 64 row-chunks
    int hb = bid >> 6, rc = bid & 63;
    int h = hb >> 1, b = hb & 1;
    int tid = threadIdx.x;
    int r = tid >> 3, c = tid & 7;
    int row = rc * 32 + r;
    size_t i0 = ((size_t)hb * 2048 + row) * 64 + c * 8;
    uint4 a0 = *(const uint4*)(po + i0);
    uint4 a1 = *(const uint4*)(po + i0 + 4194304);
    float l0 = pl[(size_t)hb * 2048 + row];
    float l1 = pl[65536 + (size_t)hb * 2048 + row];
    float inv = 1.0f / (l0 + l1);
    unsigned int* pa0 = (unsigned int*)&a0;
    unsigned int* pa1 = (unsigned int*)&a1;
    uint4 out;
    unsigned int* po_ = (unsigned int*)&out;
#pragma unroll
    for (int i = 0; i < 4; ++i) {
        float lo = (bf2f(pa0[i] & 0xffffu) + bf2f(pa1[i] & 0xffffu)) * inv;
        float hi = (bf2f(pa0[i] >> 16) + bf2f(pa1[i] >> 16)) * inv;
        po_[i] = (unsigned int)f2bf(lo) | ((unsigned int)f2bf(hi) << 16);
    }
    *(uint4*)(ao + ((size_t)(b * 2048 + row)) * 1024 + h * 64 + c * 8) = out;
}

// ---------- output projection, split-K=2, raw fp32 partials, bm-fastest ----------
__global__ __launch_bounds__(512) void k_out(
    const u16* __restrict__ ao, const u16* __restrict__ wot,
    float* __restrict__ xp0, float* __restrict__ xp1) {
    __shared__ __align__(16) u16 smem[18432];
    u16* As = smem;
    u16* Bs = smem + 8192;
    int gx = blockIdx.x, bm = gx & 31, bn = gx >> 5;
    int ksp = blockIdx.y;
    const u16* A = ao + (size_t)bm * 128 * 1024 + ksp * 512;
    const u16* B = wot + (size_t)bn * 128 * 1024 + ksp * 512;
    float* xp = ksp ? xp1 : xp0;
    int tid = threadIdx.x, wave = tid >> 6, lane = tid & 63;
    int wy = wave >> 2, wx = wave & 3, l15 = lane & 15, quad = lane >> 4;
    const u16* Ag = A + (size_t)(wave * 16 + l15) * 1024 + quad * 8;
    const u16* Bg = B + (size_t)(wave * 16 + l15) * 1024 + quad * 8;
    f32x4 acc[4][2] = {};
    gld16(Ag, As + wave * 512);
    gld16(Bg, Bs + wave * 512);
    __syncthreads();
    int buf = 0;
    for (int ks = 0; ks < 16; ++ks) {
        if (ks < 15) {
            int k0 = (ks + 1) * 32;
            gld16(Ag + k0, As + (buf ^ 1) * 4096 + wave * 512);
            gld16(Bg + k0, Bs + (buf ^ 1) * 4096 + wave * 512);
        }
        bf16x8 af[4], bfr[2];
#pragma unroll
        for (int i = 0; i < 4; ++i)
            af[i] = *(const bf16x8*)(As + buf * 4096 + (wy * 4 + i) * 512 + lane * 8);
#pragma unroll
        for (int j = 0; j < 2; ++j)
            bfr[j] = *(const bf16x8*)(Bs + buf * 4096 + (wx * 2 + j) * 512 + lane * 8);
#pragma unroll
        for (int i = 0; i < 4; ++i)
#pragma unroll
            for (int j = 0; j < 2; ++j) acc[i][j] = MFMA16(af[i], bfr[j], acc[i][j]);
        __syncthreads();
        buf ^= 1;
    }
    float* epf = (float*)smem + wave * 1152;
    int rl = lane >> 3, cg = lane & 7;
    int mbase = bm * 128 + wy * 64, nbase = bn * 128 + wx * 32;
#pragma unroll
    for (int cc = 0; cc < 2; ++cc) {
#pragma unroll
        for (int i2 = 0; i2 < 2; ++i2)
#pragma unroll
            for (int j = 0; j < 2; ++j)
#pragma unroll
                for (int r = 0; r < 4; ++r)
                    epf[(i2 * 16 + quad * 4 + r) * 36 + j * 16 + l15] =
                        acc[cc * 2 + i2][j][r];
#pragma unroll
        for (int s = 0; s < 4; ++s) {
            int row = s * 8 + rl;
            f32x4 v = *(const f32x4*)(epf + row * 36 + cg * 4);
            int m = mbase + cc * 32 + row, n = nbase + cg * 4;
            *(f32x4*)(xp + (size_t)m * 1024 + n) = v;
        }
    }
}

// ---------- layernorm + split-K sum + bias + residual ----------
__global__ __launch_bounds__(256) void k_ln(const float* __restrict__ xp0,
                                            const float* __restrict__ xp1,
                                            const float* __restrict__ resid,
                                            const float* __restrict__ bo,
                                            const float* __restrict__ gamma,
                                            const float* __restrict__ beta,
                                            float* __restrict__ out) {
    int row = blockIdx.x;
    size_t base = (size_t)row * 256;
    float4 a0 = ((const float4*)xp0)[base + threadIdx.x];
    float4 a1 = ((const float4*)xp1)[base + threadIdx.x];
    float4 rs = ((const float4*)resid)[base + threadIdx.x];
    float4 b4 = ((const float4*)bo)[threadIdx.x];
    float4 v;
    v.x = a0.x + a1.x + rs.x + b4.x;
    v.y = a0.y + a1.y + rs.y + b4.y;
    v.z = a0.z + a1.z + rs.z + b4.z;
    v.w = a0.w + a1.w + rs.w + b4.w;
    float s = v.x + v.y + v.z + v.w;
    float ss = v.x * v.x + v.y * v.y + v.z * v.z + v.w * v.w;
#pragma unroll
    for (int off = 32; off; off >>= 1) {
        s += __shfl_down(s, off, 64);
        ss += __shfl_down(ss, off, 64);
    }
    __shared__ float sb[8];
    int wave = threadIdx.x >> 6, lane = threadIdx.x & 63;
    if (lane == 0) { sb[wave] = s; sb[4 + wave] = ss; }
    __syncthreads();
    s = sb[0] + sb[1] + sb[2] + sb[3];
    ss = sb[4] + sb[5] + sb[6] + sb[7];
    float mean = s * (1.0f / 1024.0f);
    float var = fmaxf((ss - 1024.0f * mean * mean) * (1.0f / 1023.0f), 0.f);
    float inv = 1.0f / (sqrtf(var) + 1e-3f);
    float4 g = ((const float4*)gamma)[threadIdx.x];
    float4 bt = ((const float4*)beta)[threadIdx.x];
    float4 o;
    o.x = (v.x - mean) * inv * g.x + bt.x;
    o.y = (v.y - mean) * inv * g.y + bt.y;
    o.z = (v.z - mean) * inv * g.z + bt.z;
    o.w = (v.w - mean) * inv * g.w + bt.w;
    ((float4*)(out))[base + threadIdx.x] = o;
}

// ---------- launch ----------
extern "C" void kernel_launch(void* const* d_in, const int* in_sizes, int n_in,
                              void* d_out, int out_size, void* d_ws, size_t ws_size,
                              hipStream_t stream) {
    const float* v_in  = (const float*)d_in[0];
    const float* k_in  = (const float*)d_in[1];
    const float* q_in  = (const float*)d_in[2];
    const int*   mask  = (const int*)d_in[3];
    const float* w_q   = (const float*)d_in[4];
    const float* w_k   = (const float*)d_in[5];
    const float* w_v   = (const float*)d_in[6];
    const float* w_o   = (const float*)d_in[7];
    const float* b_o   = (const float*)d_in[8];
    const float* gamma = (const float*)d_in[9];
    const float* beta  = (const float*)d_in[10];
    float* out = (float*)d_out;

    char* ws = (char*)d_ws;
    const size_t MB = 1ull << 20;
    u16* qb  = (u16*)(ws + 0 * MB);
    u16* kb  = (u16*)(ws + 8 * MB);
    u16* vb  = (u16*)(ws + 16 * MB);
    u16* wqt = (u16*)(ws + 24 * MB);
    u16* wkt = (u16*)(ws + 26 * MB);
    u16* wvt = (u16*)(ws + 28 * MB);
    u16* wot = (u16*)(ws + 30 * MB);
    u16* qh  = (u16*)(ws + 32 * MB);
    u16* kh  = (u16*)(ws + 40 * MB);
    u16* vt  = (u16*)(ws + 48 * MB);
    u16* ao  = (u16*)(ws + 56 * MB);
    u64* mfrag = (u64*)(ws + 64 * MB);
    u16*   po = (u16*)(ws + 0 * MB);     // over qb/kb (dead after k_proj)
    float* pl = (float*)(ws + 16 * MB);  // over vb (dead after k_proj)
    float* xp0 = (float*)(ws + 32 * MB); // over qh/kh (dead after k_attn)
    float* xp1 = (float*)(ws + 64 * MB); // over mfrag (dead after k_attn)

    k_prep<<<dim3(18432), dim3(256), 0, stream>>>(q_in, k_in, v_in, mask,
                                                  w_q, w_k, w_v, w_o,
                                                  qb, kb, vb, mfrag,
                                                  wqt, wkt, wvt, wot);
    k_proj<<<dim3(256, 3), dim3(256), 0, stream>>>(qb, kb, vb, wqt, wkt, wvt, qh, kh, vt);
    k_attn<<<dim3(32, 16, 2), dim3(256), 0, stream>>>(qh, kh, vt, mfrag, po, pl);
    k_amerge<<<dim3(2048), dim3(256), 0, stream>>>(po, pl, ao);
    k_out<<<dim3(256, 2), dim3(512), 0, stream>>>(ao, wot, xp0, xp1);
    k_ln<<<dim3(4096), dim3(256), 0, stream>>>(xp0, xp1, k_in, b_o, gamma, beta, out);
}

// Round 10
// 287.319 us; speedup vs baseline: 1.0751x; 1.0094x over previous
//
#include <hip/hip_runtime.h>
#include <math.h>

// ---------- types ----------
typedef __bf16 bf16_t;
typedef bf16_t bf16x8 __attribute__((ext_vector_type(8)));
typedef float  f32x4  __attribute__((ext_vector_type(4)));
typedef unsigned short u16;
typedef u16 ushortx4 __attribute__((ext_vector_type(4)));
typedef unsigned long long u64;
typedef unsigned int u32x4 __attribute__((ext_vector_type(4)));

#define MFMA16(a, b, c) __builtin_amdgcn_mfma_f32_16x16x32_bf16((a), (b), (c), 0, 0, 0)

__device__ __forceinline__ u16 f2bf(float f) {
    unsigned int u = __float_as_uint(f);
    u = (u + 0x7fffu + ((u >> 16) & 1u)) >> 16;
    return (u16)u;
}

__device__ __forceinline__ float bf2f(unsigned int u) {
    return __uint_as_float(u << 16);
}

// async global->LDS, 16B per lane; lds dest = wave-uniform base + lane*16
__device__ __forceinline__ void gld16(const u16* g, u16* l) {
    __builtin_amdgcn_global_load_lds(
        (const __attribute__((address_space(1))) void*)g,
        (__attribute__((address_space(3))) void*)l, 16, 0, 0);
}

// B=2, L=2048, D_MODEL=1024, H=16, DH=64, HB=32
// ws map (MB):  [phase-aware reuse]
//  qb 0-8, kb 8-16, vb 16-24        (dead after k_proj)
//  wqt 24-26 wkt 26-28 wvt 28-30    (dead after k_proj)
//  wot 30-32                        (alive until k_out)
//  qh 32-40 (scaled by log2e/8), kh 40-48, vt 48-56 (dead after k_attn)
//  ao 56-64                          (alive until k_out)
//  mfrag 64-65                       (dead after k_attn)
//  po 0-16 (over qb/kb), pl 16-17 (over vb)   [k_attn out, dead after k_amerge]
//  xp0 32-48 (over qh/kh), xp1 64-80 (over mfrag)  [k_out partials -> k_ln]
//
// K-row permutation pi (within each 64-row K tile), applied at k_attn staging:
//   M-position m = [t1 t0 q1 q0 r1 r0] holds K-row pi(m) = [t1 q1 q0 t0 r1 r0].
// Score-MFMA slot (t, quad, r) then carries k = (t>>1)*32 + quad*8 + (t&1)*4 + r,
// so each lane's 16 P values are exactly its two 8-wide PV A-fragment slices:
// P routing is pure intra-lane register packing (verified round 3).
//
// mfrag: fragment-ordered mask words (verified round 5). Word
// W = ((b*64+qbi)*32 + ktile)*32 + hfo*16 + (t*4+r); bit L=(quad*16+l15) of W =
//   mask[b][qbi*32 + hfo*16 + l15][ktile*64 + quad*8 + (t>>1)*32 + (t&1)*4 + r]
// k_attn applies each word with ONE v_cndmask_b32 from an SGPR pair.
//
// Round 10: r9 verified base. ONE change: l row-sum via ones-MFMA
// (D[m][n] = sum_k P[m][k], replicated over n; output row=quad*4+r matches the
// pl store) replacing 15 dependent VALU adds/kt·hf + the epilogue shuffle
// reduce. Moves work from the contended VALU pipe to the 21%-busy MFMA pipe.

// ---------- fused: fp32->bf16 cvt for q,k,v + pi-ordered mask ballots + weight transposes ----------
__global__ __launch_bounds__(256) void k_prep(const float* __restrict__ q,
                                              const float* __restrict__ k,
                                              const float* __restrict__ v,
                                              const int* __restrict__ mask,
                                              const float* __restrict__ w_q,
                                              const float* __restrict__ w_k,
                                              const float* __restrict__ w_v,
                                              const float* __restrict__ w_o,
                                              u16* __restrict__ qb,
                                              u16* __restrict__ kb,
                                              u16* __restrict__ vb,
                                              u64* __restrict__ mfrag,
                                              u16* __restrict__ wqt,
                                              u16* __restrict__ wkt,
                                              u16* __restrict__ wvt,
                                              u16* __restrict__ wot) {
    __shared__ float tile[32][33];
    int bid = blockIdx.x;
    if (bid < 12288) {
        int sel = bid >> 12;                 // 0..2
        int i = (bid & 4095) * 256 + threadIdx.x;
        const float* src = sel == 0 ? q : (sel == 1 ? k : v);
        u16* dst = sel == 0 ? qb : (sel == 1 ? kb : vb);
        float4 val = ((const float4*)src)[i];
        ushortx4 r;
        r[0] = f2bf(val.x); r[1] = f2bf(val.y); r[2] = f2bf(val.z); r[3] = f2bf(val.w);
        ((ushortx4*)dst)[i] = r;
    } else if (bid < 14336) {
        // pi-ordered fragment mask ballots (see header comment)
        int wave = threadIdx.x >> 6, lane = threadIdx.x & 63;
        int l15 = lane & 15, quad = lane >> 4;
        int wt = (bid - 12288) * 4 + wave;   // [0, 8192)
        int hf = wt & 1;
        int g = wt >> 1;                     // (b*64+qbi)*32 + ktile
        int ktile = g & 31, qbi = (g >> 5) & 63, b = g >> 11;
        int qq = qbi * 32 + hf * 16 + l15;
        const int* mrow = mask + ((size_t)(b * 2048 + qq)) * 2048 + ktile * 64 + quad * 8;
        u64 myw = 0;
#pragma unroll
        for (int t = 0; t < 4; ++t)
#pragma unroll
            for (int r = 0; r < 4; ++r) {
                int m = mrow[(t >> 1) * 32 + (t & 1) * 4 + r];
                u64 bal = __ballot(m != 0);
                if (lane == t * 4 + r) myw = bal;
            }
        if (lane < 16) mfrag[(size_t)g * 32 + hf * 16 + lane] = myw;
    } else {
        int b3 = bid - 14336;
        const float* src;
        u16* dst;
        int r0, c0, C;
        if (b3 < 3072) {
            int x = b3 & 31, y = (b3 >> 5) & 1, z = b3 >> 6;
            int h = z & 15, sel = z >> 4;
            src = (sel == 0 ? w_q : (sel == 1 ? w_k : w_v)) + (size_t)h * 65536;
            dst = (sel == 0 ? wqt : (sel == 1 ? wkt : wvt)) + (size_t)h * 65536;
            r0 = x * 32; c0 = y * 32; C = 64;
        } else {
            int t = b3 - 3072;
            r0 = (t & 31) * 32; c0 = (t >> 5) * 32; C = 1024;
            src = w_o; dst = wot;
        }
        int tx = threadIdx.x & 31, ty = threadIdx.x >> 5;
        const float* s = src + ((size_t)r0) * C + c0;
#pragma unroll
        for (int i = 0; i < 4; ++i) tile[ty + i * 8][tx] = s[(ty + i * 8) * (size_t)C + tx];
        __syncthreads();
        u16* d = dst + ((size_t)c0) * 1024 + r0;
#pragma unroll
        for (int i = 0; i < 4; ++i) d[(ty + i * 8) * 1024 + tx] = f2bf(tile[tx][ty + i * 8]);
    }
}

// ---------- GEMM core body (uses As, Bs u16* into shared) ----------
#define GEMM_CORE(Ablk, Bblk, ACC)                                                    \
    int c0 = wave * 2;                                                                \
    const u16* Ag0 = Ablk + (size_t)(c0 * 16 + l15) * 1024 + quad * 8;                \
    const u16* Ag1 = Ablk + (size_t)((c0 + 1) * 16 + l15) * 1024 + quad * 8;          \
    const u16* Bg0 = Bblk + (size_t)(c0 * 16 + l15) * 1024 + quad * 8;                \
    const u16* Bg1 = Bblk + (size_t)((c0 + 1) * 16 + l15) * 1024 + quad * 8;          \
    gld16(Ag0, As + c0 * 512); gld16(Ag1, As + (c0 + 1) * 512);                       \
    gld16(Bg0, Bs + c0 * 512); gld16(Bg1, Bs + (c0 + 1) * 512);                       \
    __syncthreads();                                                                  \
    int buf = 0;                                                                      \
    for (int ks = 0; ks < 32; ++ks) {                                                 \
        if (ks < 31) {                                                                \
            int k0 = (ks + 1) * 32;                                                   \
            gld16(Ag0 + k0, As + (buf ^ 1) * 4096 + c0 * 512);                        \
            gld16(Ag1 + k0, As + (buf ^ 1) * 4096 + (c0 + 1) * 512);                  \
            gld16(Bg0 + k0, Bs + (buf ^ 1) * 4096 + c0 * 512);                        \
            gld16(Bg1 + k0, Bs + (buf ^ 1) * 4096 + (c0 + 1) * 512);                  \
        }                                                                             \
        bf16x8 af[4], bfr[4];                                                         \
        _Pragma("unroll")                                                             \
        for (int i = 0; i < 4; ++i)                                                   \
            af[i] = *(const bf16x8*)(As + buf * 4096 + (wy * 4 + i) * 512 + lane * 8);\
        _Pragma("unroll")                                                             \
        for (int j = 0; j < 4; ++j)                                                   \
            bfr[j] = *(const bf16x8*)(Bs + buf * 4096 + (wx * 4 + j) * 512 + lane * 8);\
        _Pragma("unroll")                                                             \
        for (int i = 0; i < 4; ++i)                                                   \
            _Pragma("unroll")                                                         \
            for (int j = 0; j < 4; ++j) ACC[i][j] = MFMA16(af[i], bfr[j], ACC[i][j]); \
        __syncthreads();                                                              \
        buf ^= 1;                                                                     \
    }

// ---------- fused q/k/v projections, XCD-local A-tile reuse ----------
__global__ __launch_bounds__(256) void k_proj(
    const u16* __restrict__ qb, const u16* __restrict__ kb, const u16* __restrict__ vb,
    const u16* __restrict__ wqt, const u16* __restrict__ wkt, const u16* __restrict__ wvt,
    u16* __restrict__ oq, u16* __restrict__ okh, u16* __restrict__ ovt) {
    __shared__ __align__(16) u16 smem[18432];
    u16* As = smem;
    u16* Bs = smem + 8192;
    int z = blockIdx.y, gx = blockIdx.x;
    int bm, bn;
    const u16 *A, *B;
    // fastest-varying index = tile of the LARGE matrix -> its readers co-locate per XCD
    if (z == 0)      { bm = gx & 31; bn = gx >> 5; A = qb; B = wqt; }
    else if (z == 1) { bm = gx & 31; bn = gx >> 5; A = kb; B = wkt; }
    else             { bn = gx & 31; bm = gx >> 5; A = wvt; B = vb; }
    A += (size_t)bm * 128 * 1024;
    B += (size_t)bn * 128 * 1024;
    int tid = threadIdx.x, wave = tid >> 6, lane = tid & 63;
    int wy = wave >> 1, wx = wave & 1, l15 = lane & 15, quad = lane >> 4;
    f32x4 acc[4][4] = {};
    GEMM_CORE(A, B, acc)
    u16* ep = smem + wave * 4608;
    float mulf = (z == 0) ? 0.18033688011112042f : 1.0f;
#pragma unroll
    for (int i = 0; i < 4; ++i)
#pragma unroll
        for (int j = 0; j < 4; ++j)
#pragma unroll
            for (int r = 0; r < 4; ++r)
                ep[(i * 16 + quad * 4 + r) * 72 + j * 16 + l15] = f2bf(acc[i][j][r] * mulf);
    int rl = lane >> 3, cg = lane & 7;
    if (z < 2) {
        int hh = bn * 2 + wx;
        int m0 = bm * 128 + wy * 64;
        int bb = m0 >> 11, l0 = m0 & 2047;
        u16* O = (z ? okh : oq) + ((size_t)((hh * 2 + bb) * 2048 + l0)) * 64;
#pragma unroll
        for (int s = 0; s < 8; ++s) {
            int row = s * 8 + rl;
            uint4 v = *(const uint4*)(ep + row * 72 + cg * 8);
            *(uint4*)(O + (size_t)row * 64 + cg * 8) = v;
        }
    } else {
        int m0 = bm * 128 + wy * 64;
        int hh = m0 >> 6;
        int n0 = bn * 128 + wx * 64;
        int bb = n0 >> 11, l0 = n0 & 2047;
        u16* O = ovt + (size_t)(hh * 2 + bb) * 131072 + (size_t)(m0 & 63) * 2048 + l0;
#pragma unroll
        for (int s = 0; s < 8; ++s) {
            int row = s * 8 + rl;
            uint4 v = *(const uint4*)(ep + row * 72 + cg * 8);
            *(uint4*)(O + (size_t)row * 2048 + cg * 8) = v;
        }
    }
}

// ---------- flash attention: split-K=2, hb-fastest grid (XCD-local K/V) ----------
// grid (32 hb, 16 qt, 2 ks); 256 thr = 4 waves x 32 Q-rows
// pi-permuted K staging (r3) -> P in registers; mfrag SGPR-cndmask mask (r5);
// compiler-cast P pack (r9); l row-sum via ones-MFMA (this round).
__global__ __launch_bounds__(256) void k_attn(
    const u16* __restrict__ qh, const u16* __restrict__ kh,
    const u16* __restrict__ vt, const u64* __restrict__ mfrag,
    u16* __restrict__ po, float* __restrict__ pl) {
    int hb = blockIdx.x, qt = blockIdx.y, ksp = blockIdx.z;
    int b = hb & 1;
    int tid = threadIdx.x, wave = tid >> 6, lane = tid & 63;
    int l15 = lane & 15, quad = lane >> 4;

    __shared__ __align__(16) u16 Ks[2][4096], Vs[2][4096];
    __shared__ __align__(16) u16 Eb[4][1024];   // epilogue scratch (swizzled)

    int qrow0 = qt * 128 + wave * 32;
    const u16* Qp = qh + ((size_t)(hb * 2048) + qrow0 + l15) * 64 + quad * 8;
    bf16x8 qf[2][2];
    qf[0][0] = *(const bf16x8*)Qp;
    qf[0][1] = *(const bf16x8*)(Qp + 32);
    qf[1][0] = *(const bf16x8*)(Qp + 1024);
    qf[1][1] = *(const bf16x8*)(Qp + 1024 + 32);

    int c0 = wave * 2;
    // pi-permuted K-row for this staging lane: [w1 l3 l2 w0 l1 l0]
    int rowp = (wave >> 1) * 32 + (l15 >> 2) * 8 + (wave & 1) * 4 + (l15 & 3);
    const u16* Kg0 = kh + (size_t)hb * 131072 + (size_t)ksp * 65536 +
                     (size_t)rowp * 64 + quad * 8;
    const u16* Kg1 = Kg0 + 32;
    const u16* Vg0 = vt + (size_t)hb * 131072 + (size_t)(wave * 16 + l15) * 2048 +
                     ksp * 1024 + quad * 8;
    const u16* Vg1 = Vg0 + 32;

    // wave-uniform mask-word pointer in constant addrspace -> s_load (SALU pipe)
    int wu = __builtin_amdgcn_readfirstlane(wave);
    const __attribute__((address_space(4))) u64* Mw =
        (const __attribute__((address_space(4))) u64*)(mfrag +
            (size_t)(((b * 64 + qt * 4 + wu) * 32 + ksp * 16) * 32));

    f32x4 o[2][4] = {};
    f32x4 ol[2] = {};
    u32x4 onesw = {0x3F803F80u, 0x3F803F80u, 0x3F803F80u, 0x3F803F80u};
    bf16x8 ones = *(const bf16x8*)&onesw;
    float neg = -3e30f;

    gld16(Kg0, &Ks[0][c0 * 512]);
    gld16(Kg1, &Ks[0][(c0 + 1) * 512]);
    gld16(Vg0, &Vs[0][c0 * 512]);
    gld16(Vg1, &Vs[0][(c0 + 1) * 512]);
    __syncthreads();
    int buf = 0;
    for (int kt = 0; kt < 16; ++kt) {
        if (kt < 15) {
            gld16(Kg0 + (size_t)(kt + 1) * 4096, &Ks[buf ^ 1][c0 * 512]);
            gld16(Kg1 + (size_t)(kt + 1) * 4096, &Ks[buf ^ 1][(c0 + 1) * 512]);
            gld16(Vg0 + (size_t)(kt + 1) * 64, &Vs[buf ^ 1][c0 * 512]);
            gld16(Vg1 + (size_t)(kt + 1) * 64, &Vs[buf ^ 1][(c0 + 1) * 512]);
        }
        bf16x8 kf[8], vf[8];
#pragma unroll
        for (int c = 0; c < 8; ++c) kf[c] = *(const bf16x8*)&Ks[buf][c * 512 + lane * 8];
#pragma unroll
        for (int c = 0; c < 8; ++c) vf[c] = *(const bf16x8*)&Vs[buf][c * 512 + lane * 8];
#pragma unroll
        for (int hf = 0; hf < 2; ++hf) {
            u64 mw[16];
#pragma unroll
            for (int i = 0; i < 16; ++i) mw[i] = Mw[kt * 32 + hf * 16 + i];
            f32x4 st[4] = {};
#pragma unroll
            for (int t = 0; t < 4; ++t) {
                st[t] = MFMA16(kf[t * 2], qf[hf][0], st[t]);
                st[t] = MFMA16(kf[t * 2 + 1], qf[hf][1], st[t]);
            }
            // one cndmask per element: bit[lane] of mfrag word (t*4+r) selects -3e30
            float p[16];
#pragma unroll
            for (int t = 0; t < 4; ++t)
#pragma unroll
                for (int r = 0; r < 4; ++r) {
                    float sc;
                    asm("v_cndmask_b32 %0, %1, %2, %3"
                        : "=v"(sc)
                        : "v"(st[t][r]), "v"(neg), "s"(mw[t * 4 + r]));
                    p[t * 4 + r] = __builtin_amdgcn_exp2f(sc);
                }
            // PV A-fragments = p[0..7] and p[8..15] in element order; compiler
            // picks the f32->bf16 conversions (verified r9).
            union { bf16_t e[8]; bf16x8 v; } p0u, p1u;
#pragma unroll
            for (int i = 0; i < 8; ++i) {
                p0u.e[i] = (bf16_t)p[i];
                p1u.e[i] = (bf16_t)p[8 + i];
            }
            // l row-sum on the MFMA pipe: D[m][n] = sum_k P[m][k] (replicated
            // over n); output row = quad*4+r matches the pl store below.
            ol[0 + 0] = hf ? ol[0] : MFMA16(p0u.v, ones, ol[0]);   // placeholder no-op guard
#pragma unroll
            for (int t = 0; t < 4; ++t) {
                o[hf][t] = MFMA16(p0u.v, vf[t * 2], o[hf][t]);
                o[hf][t] = MFMA16(p1u.v, vf[t * 2 + 1], o[hf][t]);
            }
            if (hf) {
                ol[1] = MFMA16(p0u.v, ones, ol[1]);
                ol[1] = MFMA16(p1u.v, ones, ol[1]);
            } else {
                ol[0] = MFMA16(p1u.v, ones, ol[0]);
            }
        }
        __syncthreads();
        buf ^= 1;
    }
    // ---- store partial l + unnormalized partial O (coalesced via swizzled Eb) ----
    size_t rowbase = ((size_t)ksp * 32 + hb) * 2048 + qrow0;
    int rl = lane >> 3, cg = lane & 7;
#pragma unroll
    for (int hf = 0; hf < 2; ++hf) {
        // ol[hf][r] = l for q-row quad*4+r (replicated across l15)
        if (l15 == 0) *(f32x4*)(pl + rowbase + hf * 16 + quad * 4) = ol[hf];
#pragma unroll
        for (int t = 0; t < 4; ++t)
#pragma unroll
            for (int r = 0; r < 4; ++r) {
                int row = quad * 4 + r, col = t * 16 + l15;
                int g = col >> 3;
                Eb[wave][row * 64 + ((g ^ (row & 7)) << 3) + (col & 7)] =
                    f2bf(o[hf][t][r]);
            }
#pragma unroll
        for (int s = 0; s < 2; ++s) {
            int row = s * 8 + rl;
            uint4 v = *(const uint4*)&Eb[wave][row * 64 + ((cg ^ (row & 7)) << 3)];
            *(uint4*)(po + (rowbase + hf * 16 + row) * 64 + cg * 8) = v;
        }
    }
}

// ---------- split-K merge: ao = (po0+po1)/(l0+l1) ----------
__global__ __launch_bounds__(256) void k_amerge(const u16* __restrict__ po,
                                                const float* __restrict__ pl,
                                                u16* __restrict__ ao) {
    int bid = blockIdx.x;               // 32 hb x 64 row-chunks
    int hb = bid >> 6, rc = bid & 63;
    int h = hb >> 1, b = hb & 1;
    int tid = threadIdx.x;
    int r = tid >> 3, c = tid & 7;
    int row = rc * 32 + r;
    size_t i0 = ((size_t)hb * 2048 + row) * 64 + c * 8;
    uint4 a0 = *(const uint4*)(po + i0);
    uint4 a1 = *(const uint4*)(po + i0 + 4194304);
    float l0 = pl[(size_t)hb * 2048 + row];
    float l1 = pl[65536 + (size_t)hb * 2048 + row];
    float inv = 1.0f / (l0 + l1);
    unsigned int* pa0 = (unsigned int*)&a0;
    unsigned int* pa1 = (unsigned int*)&a1;
    uint4 out;
    unsigned int* po_ = (unsigned int*)&out;
#pragma unroll
    for (int i = 0; i < 4; ++i) {
        float lo = (bf2f(pa0[i] & 0xffffu) + bf2f(pa1[i] & 0xffffu)) * inv;
        float hi = (bf2f(pa0[i] >> 16) + bf2f(pa1[i] >> 16)) * inv;
        po_[i] = (unsigned int)f2bf(lo) | ((unsigned int)f2bf(hi) << 16);
    }
    *(uint4*)(ao + ((size_t)(b * 2048 + row)) * 1024 + h * 64 + c * 8) = out;
}

// ---------- output projection, split-K=2, raw fp32 partials, bm-fastest ----------
__global__ __launch_bounds__(512) void k_out(
    const u16* __restrict__ ao, const u16* __restrict__ wot,
    float* __restrict__ xp0, float* __restrict__ xp1) {
    __shared__ __align__(16) u16 smem[18432];
    u16* As = smem;
    u16* Bs = smem + 8192;
    int gx = blockIdx.x, bm = gx & 31, bn = gx >> 5;
    int ksp = blockIdx.y;
    const u16* A = ao + (size_t)bm * 128 * 1024 + ksp * 512;
    const u16* B = wot + (size_t)bn * 128 * 1024 + ksp * 512;
    float* xp = ksp ? xp1 : xp0;
    int tid = threadIdx.x, wave = tid >> 6, lane = tid & 63;
    int wy = wave >> 2, wx = wave & 3, l15 = lane & 15, quad = lane >> 4;
    const u16* Ag = A + (size_t)(wave * 16 + l15) * 1024 + quad * 8;
    const u16* Bg = B + (size_t)(wave * 16 + l15) * 1024 + quad * 8;
    f32x4 acc[4][2] = {};
    gld16(Ag, As + wave * 512);
    gld16(Bg, Bs + wave * 512);
    __syncthreads();
    int buf = 0;
    for (int ks = 0; ks < 16; ++ks) {
        if (ks < 15) {
            int k0 = (ks + 1) * 32;
            gld16(Ag + k0, As + (buf ^ 1) * 4096 + wave * 512);
            gld16(Bg + k0, Bs + (buf ^ 1) * 4096 + wave * 512);
        }
        bf16x8 af[4], bfr[2];
#pragma unroll
        for (int i = 0; i < 4; ++i)
            af[i] = *(const bf16x8*)(As + buf * 4096 + (wy * 4 + i) * 512 + lane * 8);
#pragma unroll
        for (int j = 0; j < 2; ++j)
            bfr[j] = *(const bf16x8*)(Bs + buf * 4096 + (wx * 2 + j) * 512 + lane * 8);
#pragma unroll
        for (int i = 0; i < 4; ++i)
#pragma unroll
            for (int j = 0; j < 2; ++j) acc[i][j] = MFMA16(af[i], bfr[j], acc[i][j]);
        __syncthreads();
        buf ^= 1;
    }
    float* epf = (float*)smem + wave * 1152;
    int rl = lane >> 3, cg = lane & 7;
    int mbase = bm * 128 + wy * 64, nbase = bn * 128 + wx * 32;
#pragma unroll
    for (int cc = 0; cc < 2; ++cc) {
#pragma unroll
        for (int i2 = 0; i2 < 2; ++i2)
#pragma unroll
            for (int j = 0; j < 2; ++j)
#pragma unroll
                for (int r = 0; r < 4; ++r)
                    epf[(i2 * 16 + quad * 4 + r) * 36 + j * 16 + l15] =
                        acc[cc * 2 + i2][j][r];
#pragma unroll
        for (int s = 0; s < 4; ++s) {
            int row = s * 8 + rl;
            f32x4 v = *(const f32x4*)(epf + row * 36 + cg * 4);
            int m = mbase + cc * 32 + row, n = nbase + cg * 4;
            *(f32x4*)(xp + (size_t)m * 1024 + n) = v;
        }
    }
}

// ---------- layernorm + split-K sum + bias + residual ----------
__global__ __launch_bounds__(256) void k_ln(const float* __restrict__ xp0,
                                            const float* __restrict__ xp1,
                                            const float* __restrict__ resid,
                                            const float* __restrict__ bo,
                                            const float* __restrict__ gamma,
                                            const float* __restrict__ beta,
                                            float* __restrict__ out) {
    int row = blockIdx.x;
    size_t base = (size_t)row * 256;
    float4 a0 = ((const float4*)xp0)[base + threadIdx.x];
    float4 a1 = ((const float4*)xp1)[base + threadIdx.x];
    float4 rs = ((const float4*)resid)[base + threadIdx.x];
    float4 b4 = ((const float4*)bo)[threadIdx.x];
    float4 v;
    v.x = a0.x + a1.x + rs.x + b4.x;
    v.y = a0.y + a1.y + rs.y + b4.y;
    v.z = a0.z + a1.z + rs.z + b4.z;
    v.w = a0.w + a1.w + rs.w + b4.w;
    float s = v.x + v.y + v.z + v.w;
    float ss = v.x * v.x + v.y * v.y + v.z * v.z + v.w * v.w;
#pragma unroll
    for (int off = 32; off; off >>= 1) {
        s += __shfl_down(s, off, 64);
        ss += __shfl_down(ss, off, 64);
    }
    __shared__ float sb[8];
    int wave = threadIdx.x >> 6, lane = threadIdx.x & 63;
    if (lane == 0) { sb[wave] = s; sb[4 + wave] = ss; }
    __syncthreads();
    s = sb[0] + sb[1] + sb[2] + sb[3];
    ss = sb[4] + sb[5] + sb[6] + sb[7];
    float mean = s * (1.0f / 1024.0f);
    float var = fmaxf((ss - 1024.0f * mean * mean) * (1.0f / 1023.0f), 0.f);
    float inv = 1.0f / (sqrtf(var) + 1e-3f);
    float4 g = ((const float4*)gamma)[threadIdx.x];
    float4 bt = ((const float4*)beta)[threadIdx.x];
    float4 o;
    o.x = (v.x - mean) * inv * g.x + bt.x;
    o.y = (v.y - mean) * inv * g.y + bt.y;
    o.z = (v.z - mean) * inv * g.z + bt.z;
    o.w = (v.w - mean) * inv * g.w + bt.w;
    ((float4*)(out))[base + threadIdx.x] = o;
}

// ---------- launch ----------
extern "C" void kernel_launch(void* const* d_in, const int* in_sizes, int n_in,
                              void* d_out, int out_size, void* d_ws, size_t ws_size,
                              hipStream_t stream) {
    const float* v_in  = (const float*)d_in[0];
    const float* k_in  = (const float*)d_in[1];
    const float* q_in  = (const float*)d_in[2];
    const int*   mask  = (const int*)d_in[3];
    const float* w_q   = (const float*)d_in[4];
    const float* w_k   = (const float*)d_in[5];
    const float* w_v   = (const float*)d_in[6];
    const float* w_o   = (const float*)d_in[7];
    const float* b_o   = (const float*)d_in[8];
    const float* gamma = (const float*)d_in[9];
    const float* beta  = (const float*)d_in[10];
    float* out = (float*)d_out;

    char* ws = (char*)d_ws;
    const size_t MB = 1ull << 20;
    u16* qb  = (u16*)(ws + 0 * MB);
    u16* kb  = (u16*)(ws + 8 * MB);
    u16* vb  = (u16*)(ws + 16 * MB);
    u16* wqt = (u16*)(ws + 24 * MB);
    u16* wkt = (u16*)(ws + 26 * MB);
    u16* wvt = (u16*)(ws + 28 * MB);
    u16* wot = (u16*)(ws + 30 * MB);
    u16* qh  = (u16*)(ws + 32 * MB);
    u16* kh  = (u16*)(ws + 40 * MB);
    u16* vt  = (u16*)(ws + 48 * MB);
    u16* ao  = (u16*)(ws + 56 * MB);
    u64* mfrag = (u64*)(ws + 64 * MB);
    u16*   po = (u16*)(ws + 0 * MB);     // over qb/kb (dead after k_proj)
    float* pl = (float*)(ws + 16 * MB);  // over vb (dead after k_proj)
    float* xp0 = (float*)(ws + 32 * MB); // over qh/kh (dead after k_attn)
    float* xp1 = (float*)(ws + 64 * MB); // over mfrag (dead after k_attn)

    k_prep<<<dim3(18432), dim3(256), 0, stream>>>(q_in, k_in, v_in, mask,
                                                  w_q, w_k, w_v, w_o,
                                                  qb, kb, vb, mfrag,
                                                  wqt, wkt, wvt, wot);
    k_proj<<<dim3(256, 3), dim3(256), 0, stream>>>(qb, kb, vb, wqt, wkt, wvt, qh, kh, vt);
    k_attn<<<dim3(32, 16, 2), dim3(256), 0, stream>>>(qh, kh, vt, mfrag, po, pl);
    k_amerge<<<dim3(2048), dim3(256), 0, stream>>>(po, pl, ao);
    k_out<<<dim3(256, 2), dim3(512), 0, stream>>>(ao, wot, xp0, xp1);
    k_ln<<<dim3(4096), dim3(256), 0, stream>>>(xp0, xp1, k_in, b_o, gamma, beta, out);
}